// Round 10
// baseline (414.719 us; speedup 1.0000x reference)
//
#include <hip/hip_runtime.h>
#include <hip/hip_bf16.h>

#define DEVFN __device__ __forceinline__

typedef __bf16 bf16x8 __attribute__((ext_vector_type(8)));
typedef float f32x4 __attribute__((ext_vector_type(4)));
typedef unsigned short ushort8 __attribute__((ext_vector_type(8)));
typedef unsigned short us4 __attribute__((ext_vector_type(4)));

namespace {

constexpr int S = 1024;
constexpr int HID = 768;
constexpr int NH = 12;
constexpr int HD = 64;

DEVFN unsigned short f2bf(float f) {
  union { float f; unsigned u; } v; v.f = f;
  unsigned r = v.u + 0x7FFF + ((v.u >> 16) & 1);   // RNE
  return (unsigned short)(r >> 16);
}

DEVFN float bf2f(unsigned short u) {
  union { unsigned u; float f; } v; v.u = ((unsigned)u) << 16; return v.f;
}

DEVFN f32x4 zero4() { return f32x4{0.f, 0.f, 0.f, 0.f}; }

DEVFN f32x4 mfma_bf16(bf16x8 a, bf16x8 b, f32x4 c) {
  return __builtin_amdgcn_mfma_f32_16x16x32_bf16(a, b, c, 0, 0, 0);
}

// async global->LDS, 16B per lane; dest = lds_base + lane*16 (wave-uniform base)
DEVFN void gload16(void* lds_base, const void* gsrc) {
  __builtin_amdgcn_global_load_lds(
      (const __attribute__((address_space(1))) void*)gsrc,
      (__attribute__((address_space(3))) void*)lds_base, 16, 0, 0);
}

// read one MFMA fragment (8 contiguous bf16) from a [rows][64] bf16 LDS tile
// stored with chunk-XOR swizzle: LDS[row][ch] = G[row][ch ^ (row&7)]
DEVFN bf16x8 frag_ld(const char* tile, int row, int ch) {
  int chs = ch ^ (row & 7);
  return *(const bf16x8*)(tile + row * 128 + chs * 16);
}

// ---------------------------------------------------------------- K0: preps
__global__ void k0_cvt_x(const float* __restrict__ x, unsigned short* __restrict__ xb) {
  size_t i = (size_t)(blockIdx.x * 256 + threadIdx.x) * 8;
  float4 a = *(const float4*)(x + i);
  float4 c = *(const float4*)(x + i + 4);
  ushort8 o;
  o[0] = f2bf(a.x); o[1] = f2bf(a.y); o[2] = f2bf(a.z); o[3] = f2bf(a.w);
  o[4] = f2bf(c.x); o[5] = f2bf(c.y); o[6] = f2bf(c.z); o[7] = f2bf(c.w);
  *(ushort8*)(xb + i) = o;
}

// dist_emb [2047][64] f32 -> [2048][64] bf16 (row 2047 zero-padded)
__global__ void k0_cvt_pe(const float* __restrict__ de, unsigned short* __restrict__ peb) {
  size_t i = (size_t)(blockIdx.x * 256 + threadIdx.x) * 8;
  int row = (int)(i >> 6);
  ushort8 o;
  if (row < 2047) {
    float4 a = *(const float4*)(de + i);
    float4 c = *(const float4*)(de + i + 4);
    o[0] = f2bf(a.x); o[1] = f2bf(a.y); o[2] = f2bf(a.z); o[3] = f2bf(a.w);
    o[4] = f2bf(c.x); o[5] = f2bf(c.y); o[6] = f2bf(c.z); o[7] = f2bf(c.w);
  } else {
    o = ushort8{0, 0, 0, 0, 0, 0, 0, 0};
  }
  *(ushort8*)(peb + i) = o;
}

// W[k][n] f32 -> wt[sec*768+n][k] bf16  (64x64 LDS tile transpose)
__global__ __launch_bounds__(256) void k0_wt(const float* __restrict__ Wq,
                                             const float* __restrict__ Wk,
                                             const float* __restrict__ Wv,
                                             unsigned short* __restrict__ wt) {
  __shared__ float t[64][65];
  int bidx = blockIdx.x;                 // 3 * 12 * 12 = 432
  int sec = bidx / 144, rem = bidx % 144;
  int ktb = rem / 12, ntb = rem % 12;
  const float* W = (sec == 0) ? Wq : ((sec == 1) ? Wk : Wv);
  int k0 = ktb * 64, n0 = ntb * 64;
  int tid = threadIdx.x;
  #pragma unroll
  for (int p = 0; p < 4; ++p) {
    int id = p * 256 + tid;              // 0..1023
    int row = id >> 4, ch = id & 15;
    float4 v = *(const float4*)(W + (size_t)(k0 + row) * 768 + n0 + ch * 4);
    t[row][ch * 4 + 0] = v.x; t[row][ch * 4 + 1] = v.y;
    t[row][ch * 4 + 2] = v.z; t[row][ch * 4 + 3] = v.w;
  }
  __syncthreads();
  #pragma unroll
  for (int p = 0; p < 2; ++p) {
    int id = p * 256 + tid;              // 0..511
    int nrow = id >> 3, c8 = id & 7;
    ushort8 o;
    #pragma unroll
    for (int i = 0; i < 8; ++i) o[i] = f2bf(t[c8 * 8 + i][nrow]);
    *(ushort8*)(wt + (size_t)(sec * 768 + n0 + nrow) * 768 + k0 + c8 * 8) = o;
  }
}

// ------------------------------------------------- K1: fused QKV projection
// (proven 64x64-tile version; ~20us)
__global__ __launch_bounds__(256) void k1_qkv(
    const unsigned short* __restrict__ xb, const unsigned short* __restrict__ wt,
    const float* __restrict__ bq, const float* __restrict__ bk, const float* __restrict__ bv,
    unsigned short* __restrict__ q_ws, unsigned short* __restrict__ k_ws,
    unsigned short* __restrict__ vt_ws) {
  __shared__ char ldsA[8192], ldsB[8192];
  const int tid = threadIdx.x, lane = tid & 63, wv = tid >> 6;
  const int row16 = lane & 15, cgrp = lane >> 4;
  const int ntb = blockIdx.x % 36, mtb = blockIdx.x / 36;
  const int sec = ntb / 12;
  const int n0 = ntb * 64;
  const int m0 = mtb * 64;

  f32x4 acc[4] = {zero4(), zero4(), zero4(), zero4()};

  for (int k0 = 0; k0 < 768; k0 += 64) {
    #pragma unroll
    for (int c = 0; c < 2; ++c) {
      int cc = (wv * 2 + c) * 64 + lane;
      int row = cc >> 3, ch = cc & 7, chs = ch ^ (row & 7);
      gload16(ldsA + (wv * 2 + c) * 1024, xb + (size_t)(m0 + row) * 768 + k0 + chs * 8);
      gload16(ldsB + (wv * 2 + c) * 1024, wt + (size_t)(n0 + row) * 768 + k0 + chs * 8);
    }
    __syncthreads();
    if (sec < 2) {
      bf16x8 af[2];
      #pragma unroll
      for (int k2 = 0; k2 < 2; ++k2) af[k2] = frag_ld(ldsA, wv * 16 + row16, k2 * 4 + cgrp);
      #pragma unroll
      for (int nt = 0; nt < 4; ++nt)
        #pragma unroll
        for (int k2 = 0; k2 < 2; ++k2) {
          bf16x8 bf = frag_ld(ldsB, nt * 16 + row16, k2 * 4 + cgrp);
          acc[nt] = mfma_bf16(af[k2], bf, acc[nt]);
        }
    } else {
      bf16x8 af[2];
      #pragma unroll
      for (int k2 = 0; k2 < 2; ++k2) af[k2] = frag_ld(ldsB, wv * 16 + row16, k2 * 4 + cgrp);
      #pragma unroll
      for (int mt = 0; mt < 4; ++mt)
        #pragma unroll
        for (int k2 = 0; k2 < 2; ++k2) {
          bf16x8 bx = frag_ld(ldsA, mt * 16 + row16, k2 * 4 + cgrp);
          acc[mt] = mfma_bf16(af[k2], bx, acc[mt]);
        }
    }
    __syncthreads();
  }

  if (sec < 2) {
    unsigned short* dst = (sec == 0) ? q_ws : k_ws;
    const float* bias = (sec == 0) ? bq : bk;
    int nl0 = (ntb % 12) * 64;
    #pragma unroll
    for (int nt = 0; nt < 4; ++nt) {
      int nn = nl0 + nt * 16 + row16;
      float bb = bias[nn];
      int hh = nn >> 6, dd = nn & 63;
      #pragma unroll
      for (int j = 0; j < 4; ++j) {
        int m = m0 + wv * 16 + cgrp * 4 + j;
        int b_ = m >> 10, s_ = m & 1023;
        dst[(size_t)((b_ * 12 + hh) * 1024 + s_) * 64 + dd] = f2bf(acc[nt][j] + bb);
      }
    }
  } else {
    int nl0 = (ntb % 12) * 64;
    #pragma unroll
    for (int j = 0; j < 4; ++j) {
      int nn = nl0 + wv * 16 + cgrp * 4 + j;
      float bb = bv[nn];
      int hh = nn >> 6, dd = nn & 63;
      #pragma unroll
      for (int mt = 0; mt < 4; ++mt) {
        int m = m0 + mt * 16 + row16;
        int b_ = m >> 10, s_ = m & 1023;
        vt_ws[(size_t)((b_ * 12 + hh) * 64 + dd) * 1024 + s_] = f2bf(acc[mt][j] + bb);
      }
    }
  }
}

// -------- K2: one-shot 64x64 score tile -> unnormalized p + fused PV partial
// grid 12288, XCD-chunked: all 256 tiles of one bh land on one XCD (L2-local
// K/PE/V + L2-local ctx atomics). 4 waves, each a 32x32 quadrant.
// After the combine, V^T is staged into the dead K-tile LDS and each wave
// does its own-quadrant PV (8 MFMA) -> atomicAdd into ctx_acc (f32; add-order
// nondeterminism ~1e-6, far below the 1.8e-3 threshold).
__global__ __launch_bounds__(256) void k2_score(
    const unsigned short* __restrict__ q_ws, const unsigned short* __restrict__ k_ws,
    const unsigned short* __restrict__ vt_ws, const unsigned short* __restrict__ peb,
    const float* __restrict__ mask, unsigned short* __restrict__ p_out,
    float* __restrict__ rsum_part, float* __restrict__ ctx_acc) {
  __shared__ char k_lds[8192];                 // K tile; reused for V^T tile
  __shared__ char pe_lds[16384];
  __shared__ unsigned short s3t[4][64 * 36];   // per-wave bf16 [jj][r], pad 36
  __shared__ unsigned short p_sh[64 * 64];     // swizzled p tile, bf16
  __shared__ float rsum_sh[2][64];

  const int tid = threadIdx.x, lane = tid & 63, wv = tid >> 6;
  const int wl = wv >> 1, wr = wv & 1;
  const int row16 = lane & 15, cgrp = lane >> 4;

  const int bid = blockIdx.x;
  const int swz = (bid & 7) * 1536 + (bid >> 3);   // XCD-chunked (12288 = 8*1536)
  const int rt = swz & 15, lt = (swz >> 4) & 15, bh = swz >> 8;
  const int b = bh / NH;
  const int l0 = lt * 64, r0 = rt * 64;

  const unsigned short* qh = q_ws + (size_t)bh * S * HD;
  const unsigned short* khp = k_ws + (size_t)bh * S * HD;
  const unsigned short* vth = vt_ws + (size_t)bh * HD * S;
  const float* maskb = mask + b * S;

  // ---- stage K tile [64][64] and PE window [128][64] (swizzled) ----
  #pragma unroll
  for (int c = 0; c < 2; ++c) {
    int cc = (wv * 2 + c) * 64 + lane;
    int row = cc >> 3, ch = cc & 7, chs = ch ^ (row & 7);
    gload16(k_lds + (wv * 2 + c) * 1024, khp + (size_t)(r0 + row) * HD + chs * 8);
  }
  {
    int m0 = l0 - r0 + 960;  // in [0,1920]
    #pragma unroll
    for (int c = 0; c < 4; ++c) {
      int cc = (wv * 4 + c) * 64 + lane;
      int row = cc >> 3, ch = cc & 7, chs = ch ^ (row & 7);
      gload16(pe_lds + (wv * 4 + c) * 1024, peb + (size_t)(m0 + row) * HD + chs * 8);
    }
  }

  // Q fragments straight from global (overlaps with staging)
  bf16x8 qf[2][2];
  #pragma unroll
  for (int ltl = 0; ltl < 2; ++ltl)
    #pragma unroll
    for (int k2 = 0; k2 < 2; ++k2)
      qf[ltl][k2] = *(const bf16x8*)(qh + (size_t)(l0 + wl * 32 + ltl * 16 + row16) * HD +
                                     k2 * 32 + cgrp * 8);
  __syncthreads();                                       // b1: staging done

  // ---- fragment reads (K, PE -> registers) ----
  bf16x8 kf[2][2], pef[4][2];
  #pragma unroll
  for (int rtl = 0; rtl < 2; ++rtl)
    #pragma unroll
    for (int k2 = 0; k2 < 2; ++k2)
      kf[rtl][k2] = frag_ld(k_lds, wr * 32 + rtl * 16 + row16, k2 * 4 + cgrp);
  const int qb = (wl - wr) * 32 + 32;   // quadrant window base: 0 / 32 / 64
  #pragma unroll
  for (int jt = 0; jt < 4; ++jt)
    #pragma unroll
    for (int k2 = 0; k2 < 2; ++k2)
      pef[jt][k2] = frag_ld(pe_lds, qb + jt * 16 + row16, k2 * 4 + cgrp);
  __syncthreads();                                       // b2: K LDS reads done

  // ---- stage V^T tile [64d][64r] into k_lds (latency hidden by compute) ----
  #pragma unroll
  for (int c = 0; c < 2; ++c) {
    int cc = (wv * 2 + c) * 64 + lane;
    int row = cc >> 3, ch = cc & 7, chs = ch ^ (row & 7);
    gload16(k_lds + (wv * 2 + c) * 1024, vth + (size_t)row * S + r0 + chs * 8);
  }

  unsigned short* s3w = &s3t[wv][0];

  // ---- S3 = K @ PE^T -> per-wave LDS transposed [jj][r], bf16 ----
  #pragma unroll
  for (int rtl = 0; rtl < 2; ++rtl)
    #pragma unroll
    for (int jt = 0; jt < 4; ++jt) {
      f32x4 a3 = zero4();
      a3 = mfma_bf16(kf[rtl][0], pef[jt][0], a3);
      a3 = mfma_bf16(kf[rtl][1], pef[jt][1], a3);
      us4 o;
      o[0] = f2bf(a3[0]); o[1] = f2bf(a3[1]); o[2] = f2bf(a3[2]); o[3] = f2bf(a3[3]);
      *(us4*)(s3w + (jt * 16 + row16) * 36 + rtl * 16 + cgrp * 4) = o;
    }

  // ---- S1 = Q @ K^T ----
  f32x4 s1[2][2];
  #pragma unroll
  for (int ltl = 0; ltl < 2; ++ltl)
    #pragma unroll
    for (int rtl = 0; rtl < 2; ++rtl) {
      f32x4 a1 = zero4();
      a1 = mfma_bf16(qf[ltl][0], kf[rtl][0], a1);
      a1 = mfma_bf16(qf[ltl][1], kf[rtl][1], a1);
      s1[ltl][rtl] = a1;
    }
  // ---- S2 = Q @ PE^T (registers, gathered via shfl) ----
  f32x4 s2[2][4];
  #pragma unroll
  for (int ltl = 0; ltl < 2; ++ltl)
    #pragma unroll
    for (int jt = 0; jt < 4; ++jt) {
      f32x4 a2 = zero4();
      a2 = mfma_bf16(qf[ltl][0], pef[jt][0], a2);
      a2 = mfma_bf16(qf[ltl][1], pef[jt][1], a2);
      s2[ltl][jt] = a2;
    }

  // ---- combine: diag gathers + exp + p_sh + rowsum partials ----
  float rs[2][4] = {};
  #pragma unroll
  for (int rtl = 0; rtl < 2; ++rtl) {
    float mval = maskb[r0 + wr * 32 + rtl * 16 + row16];
    #pragma unroll
    for (int ltl = 0; ltl < 2; ++ltl) {
      const int jtA = ltl - rtl + 1;
      #pragma unroll
      for (int j = 0; j < 4; ++j) {
        int dl = ltl * 16 + cgrp * 4 + j;
        int dr = rtl * 16 + row16;
        int jjq = dl - dr + 31;                       // [0,62]
        int src = (lane & 48) | (jjq & 15);
        float vA = __shfl(s2[ltl][jtA][j], src, 64);
        float vB = __shfl(s2[ltl][jtA + 1][j], src, 64);
        float b1 = ((jjq >> 4) == jtA) ? vA : vB;
        float b2 = bf2f(s3w[jjq * 36 + dr]);
        float logit = (s1[ltl][rtl][j] + b1 + b2) * 0.125f + mval;
        float p = __expf(logit);
        rs[ltl][j] += p;
        int dlb = wl * 32 + dl, drb = wr * 32 + dr;
        p_sh[dlb * 64 + (drb ^ ((dlb & 7) << 3))] = f2bf(p);
      }
    }
  }

  // ---- rowsum: reduce over the 16 dr lanes -> LDS partials per wr ----
  #pragma unroll
  for (int ltl = 0; ltl < 2; ++ltl)
    #pragma unroll
    for (int j = 0; j < 4; ++j) {
      float v = rs[ltl][j];
      v += __shfl_xor(v, 1, 64);
      v += __shfl_xor(v, 2, 64);
      v += __shfl_xor(v, 4, 64);
      v += __shfl_xor(v, 8, 64);
      rs[ltl][j] = v;
    }
  if (row16 == 0) {
    #pragma unroll
    for (int ltl = 0; ltl < 2; ++ltl)
      #pragma unroll
      for (int j = 0; j < 4; ++j)
        rsum_sh[wr][wl * 32 + ltl * 16 + cgrp * 4 + j] = rs[ltl][j];
  }
  __syncthreads();                       // b3: p_sh + vlds + rsum_sh ready

  // one f32 per row per block -> [bh*16+lt][row][rt]
  if (tid < 64)
    rsum_part[((size_t)(bh * 16 + lt) * 64 + tid) * 16 + rt] =
        rsum_sh[0][tid] + rsum_sh[1][tid];

  // ---- PV partial: own quadrant p [32l][32r] x V^T tile -> atomics ----
  {
    bf16x8 pa[2];
    #pragma unroll
    for (int lt2 = 0; lt2 < 2; ++lt2) {
      int dlb = wl * 32 + lt2 * 16 + row16;
      pa[lt2] = *(const bf16x8*)(p_sh + dlb * 64 + (((wr * 4 + cgrp) ^ (dlb & 7)) * 8));
    }
    #pragma unroll
    for (int dt = 0; dt < 4; ++dt) {
      bf16x8 vb = frag_ld(k_lds, dt * 16 + row16, wr * 4 + cgrp);
      #pragma unroll
      for (int lt2 = 0; lt2 < 2; ++lt2) {
        f32x4 cc = mfma_bf16(pa[lt2], vb, zero4());
        #pragma unroll
        for (int e = 0; e < 4; ++e)
          atomicAdd(&ctx_acc[((size_t)bh * S + l0 + wl * 32 + lt2 * 16 + cgrp * 4 + e) * 64 +
                             dt * 16 + row16],
                    cc[e]);
      }
    }
  }

  // ---- coalesced p tile write-out ----
  #pragma unroll
  for (int p2 = 0; p2 < 2; ++p2) {
    int id = p2 * 256 + tid, dl = id >> 3, c = id & 7;
    uint4 w = *(const uint4*)((const char*)p_sh + dl * 128 + (c ^ (dl & 7)) * 16);
    *(uint4*)(p_out + ((size_t)bh * S + l0 + dl) * S + r0 + c * 8) = w;
  }
}

// -------- K_inv: inv[t] = 1 / sum_16(rsum_part[t])  (t = bh*1024 + l)
__global__ __launch_bounds__(256) void k_inv(const float* __restrict__ rsum_part,
                                             float* __restrict__ inv_ws) {
  int t = blockIdx.x * 256 + threadIdx.x;      // 49152
  const float4* pp = (const float4*)(rsum_part + (size_t)t * 16);
  float s = 0.f;
  #pragma unroll
  for (int i = 0; i < 4; ++i) {
    float4 v = pp[i];
    s += v.x + v.y + v.z + v.w;
  }
  inv_ws[t] = 1.0f / s;
}

// -------- K3n: streaming probs normalize  p(bf16) * inv -> f32
__global__ __launch_bounds__(256) void k3n(const unsigned short* __restrict__ p_in,
                                           const float* __restrict__ inv_ws,
                                           float* __restrict__ out_probs) {
  int gid = blockIdx.x * 256 + threadIdx.x;    // 6,291,456 threads
  int row = gid >> 7;                          // bh*1024 + l
  int c = gid & 127;
  float iv = inv_ws[row];
  ushort8 w = *(const ushort8*)(p_in + (size_t)row * 1024 + c * 8);
  float* dst = out_probs + (size_t)row * 1024 + c * 8;
  float4 lo{bf2f(w[0]) * iv, bf2f(w[1]) * iv, bf2f(w[2]) * iv, bf2f(w[3]) * iv};
  float4 hi{bf2f(w[4]) * iv, bf2f(w[5]) * iv, bf2f(w[6]) * iv, bf2f(w[7]) * iv};
  *(float4*)dst = lo;
  *(float4*)(dst + 4) = hi;
}

// -------- K5: ctx = inv * ctx_acc, relayout [bh][l][d] -> [b][l][h*64+d]
__global__ __launch_bounds__(256) void k5_fin(const float* __restrict__ ctx_acc,
                                              const float* __restrict__ inv_ws,
                                              float* __restrict__ out_ctx) {
  int gid = blockIdx.x * 256 + threadIdx.x;    // 393216
  int t = gid >> 3, d0 = (gid & 7) * 8;
  float iv = inv_ws[t];
  const float* p = ctx_acc + (size_t)t * 64 + d0;
  float4 a = *(const float4*)p;
  float4 b = *(const float4*)(p + 4);
  a.x *= iv; a.y *= iv; a.z *= iv; a.w *= iv;
  b.x *= iv; b.y *= iv; b.z *= iv; b.w *= iv;
  int bh = t >> 10, l = t & 1023;
  int b_ = bh / NH, h = bh % NH;
  float* dst = out_ctx + ((size_t)(b_ * S + l)) * HID + h * HD + d0;
  *(float4*)dst = a;
  *(float4*)(dst + 4) = b;
}

}  // namespace

extern "C" void kernel_launch(void* const* d_in, const int* in_sizes, int n_in,
                              void* d_out, int out_size, void* d_ws, size_t ws_size,
                              hipStream_t stream) {
  const float* hidden = (const float*)d_in[0];
  const float* mask   = (const float*)d_in[1];
  const float* Wq = (const float*)d_in[2];
  const float* bq = (const float*)d_in[3];
  const float* Wk = (const float*)d_in[4];
  const float* bk = (const float*)d_in[5];
  const float* Wv = (const float*)d_in[6];
  const float* bv = (const float*)d_in[7];
  const float* de = (const float*)d_in[8];

  unsigned short* ws = (unsigned short*)d_ws;
  unsigned short* q_ws  = ws;                        // 48*1024*64
  unsigned short* k_ws  = ws + 3145728;
  unsigned short* vt_ws = ws + 6291456;              // [bh][d][s]
  unsigned short* xb    = ws + 9437184;              // [4096][768]
  unsigned short* wt    = ws + 12582912;             // [2304][768]
  unsigned short* peb   = ws + 14352384;             // [2048][64]
  float* rsum_part = (float*)(ws + 14483456);        // [768][64][16] f32
  unsigned short* p_ws  = ws + 16056320;             // [bh][l][r] bf16, 96MB
  float* ctx_acc = (float*)(ws + 66387968);          // [48][1024][64] f32
  float* inv_ws  = (float*)(ws + 72679424);          // [48*1024] f32
  // end = 72777728 shorts = 145.6 MB (ws is ~816 MB per poison-fill size)

  float* outc = (float*)d_out;
  float* outp = outc + (size_t)4 * 1024 * 768;

  hipLaunchKernelGGL(k0_cvt_x, dim3(1536), dim3(256), 0, stream, hidden, xb);
  hipLaunchKernelGGL(k0_cvt_pe, dim3(64), dim3(256), 0, stream, de, peb);
  hipLaunchKernelGGL(k0_wt, dim3(432), dim3(256), 0, stream, Wq, Wk, Wv, wt);
  hipLaunchKernelGGL(k1_qkv, dim3(2304), dim3(256), 0, stream,
                     xb, wt, bq, bk, bv, q_ws, k_ws, vt_ws);
  hipMemsetAsync(ctx_acc, 0, (size_t)3145728 * 4, stream);
  hipLaunchKernelGGL(k2_score, dim3(12288), dim3(256), 0, stream,
                     q_ws, k_ws, vt_ws, peb, mask, p_ws, rsum_part, ctx_acc);
  hipLaunchKernelGGL(k_inv, dim3(192), dim3(256), 0, stream, rsum_part, inv_ws);
  hipLaunchKernelGGL(k3n, dim3(24576), dim3(256), 0, stream, p_ws, inv_ws, outp);
  hipLaunchKernelGGL(k5_fin, dim3(1536), dim3(256), 0, stream, ctx_acc, inv_ws, outc);
}

// Round 11
// 230.247 us; speedup vs baseline: 1.8012x; 1.8012x over previous
//
#include <hip/hip_runtime.h>
#include <hip/hip_bf16.h>

#define DEVFN __device__ __forceinline__

typedef __bf16 bf16x8 __attribute__((ext_vector_type(8)));
typedef float f32x4 __attribute__((ext_vector_type(4)));
typedef unsigned short ushort8 __attribute__((ext_vector_type(8)));
typedef unsigned short us4 __attribute__((ext_vector_type(4)));

namespace {

constexpr int S = 1024;
constexpr int HID = 768;
constexpr int NH = 12;
constexpr int HD = 64;

DEVFN unsigned short f2bf(float f) {
  union { float f; unsigned u; } v; v.f = f;
  unsigned r = v.u + 0x7FFF + ((v.u >> 16) & 1);   // RNE
  return (unsigned short)(r >> 16);
}

DEVFN float bf2f(unsigned short u) {
  union { unsigned u; float f; } v; v.u = ((unsigned)u) << 16; return v.f;
}

DEVFN f32x4 zero4() { return f32x4{0.f, 0.f, 0.f, 0.f}; }

DEVFN f32x4 mfma_bf16(bf16x8 a, bf16x8 b, f32x4 c) {
  return __builtin_amdgcn_mfma_f32_16x16x32_bf16(a, b, c, 0, 0, 0);
}

// async global->LDS, 16B per lane; dest = lds_base + lane*16 (wave-uniform base)
DEVFN void gload16(void* lds_base, const void* gsrc) {
  __builtin_amdgcn_global_load_lds(
      (const __attribute__((address_space(1))) void*)gsrc,
      (__attribute__((address_space(3))) void*)lds_base, 16, 0, 0);
}

// read one MFMA fragment (8 contiguous bf16) from a [rows][64] bf16 LDS tile
// stored with chunk-XOR swizzle: LDS[row][ch] = G[row][ch ^ (row&7)]
DEVFN bf16x8 frag_ld(const char* tile, int row, int ch) {
  int chs = ch ^ (row & 7);
  return *(const bf16x8*)(tile + row * 128 + chs * 16);
}

// ---------------------------------------------------------------- K0: preps
__global__ void k0_cvt_x(const float* __restrict__ x, unsigned short* __restrict__ xb) {
  size_t i = (size_t)(blockIdx.x * 256 + threadIdx.x) * 8;
  float4 a = *(const float4*)(x + i);
  float4 c = *(const float4*)(x + i + 4);
  ushort8 o;
  o[0] = f2bf(a.x); o[1] = f2bf(a.y); o[2] = f2bf(a.z); o[3] = f2bf(a.w);
  o[4] = f2bf(c.x); o[5] = f2bf(c.y); o[6] = f2bf(c.z); o[7] = f2bf(c.w);
  *(ushort8*)(xb + i) = o;
}

// dist_emb [2047][64] f32 -> [2048][64] bf16 (row 2047 zero-padded)
__global__ void k0_cvt_pe(const float* __restrict__ de, unsigned short* __restrict__ peb) {
  size_t i = (size_t)(blockIdx.x * 256 + threadIdx.x) * 8;
  int row = (int)(i >> 6);
  ushort8 o;
  if (row < 2047) {
    float4 a = *(const float4*)(de + i);
    float4 c = *(const float4*)(de + i + 4);
    o[0] = f2bf(a.x); o[1] = f2bf(a.y); o[2] = f2bf(a.z); o[3] = f2bf(a.w);
    o[4] = f2bf(c.x); o[5] = f2bf(c.y); o[6] = f2bf(c.z); o[7] = f2bf(c.w);
  } else {
    o = ushort8{0, 0, 0, 0, 0, 0, 0, 0};
  }
  *(ushort8*)(peb + i) = o;
}

// W[k][n] f32 -> wt[sec*768+n][k] bf16  (64x64 LDS tile transpose)
__global__ __launch_bounds__(256) void k0_wt(const float* __restrict__ Wq,
                                             const float* __restrict__ Wk,
                                             const float* __restrict__ Wv,
                                             unsigned short* __restrict__ wt) {
  __shared__ float t[64][65];
  int bidx = blockIdx.x;                 // 3 * 12 * 12 = 432
  int sec = bidx / 144, rem = bidx % 144;
  int ktb = rem / 12, ntb = rem % 12;
  const float* W = (sec == 0) ? Wq : ((sec == 1) ? Wk : Wv);
  int k0 = ktb * 64, n0 = ntb * 64;
  int tid = threadIdx.x;
  #pragma unroll
  for (int p = 0; p < 4; ++p) {
    int id = p * 256 + tid;              // 0..1023
    int row = id >> 4, ch = id & 15;
    float4 v = *(const float4*)(W + (size_t)(k0 + row) * 768 + n0 + ch * 4);
    t[row][ch * 4 + 0] = v.x; t[row][ch * 4 + 1] = v.y;
    t[row][ch * 4 + 2] = v.z; t[row][ch * 4 + 3] = v.w;
  }
  __syncthreads();
  #pragma unroll
  for (int p = 0; p < 2; ++p) {
    int id = p * 256 + tid;              // 0..511
    int nrow = id >> 3, c8 = id & 7;
    ushort8 o;
    #pragma unroll
    for (int i = 0; i < 8; ++i) o[i] = f2bf(t[c8 * 8 + i][nrow]);
    *(ushort8*)(wt + (size_t)(sec * 768 + n0 + nrow) * 768 + k0 + c8 * 8) = o;
  }
}

// ------------------------------------------------- K1: fused QKV projection
// (proven 64x64-tile version)
__global__ __launch_bounds__(256) void k1_qkv(
    const unsigned short* __restrict__ xb, const unsigned short* __restrict__ wt,
    const float* __restrict__ bq, const float* __restrict__ bk, const float* __restrict__ bv,
    unsigned short* __restrict__ q_ws, unsigned short* __restrict__ k_ws,
    unsigned short* __restrict__ vt_ws) {
  __shared__ char ldsA[8192], ldsB[8192];
  const int tid = threadIdx.x, lane = tid & 63, wv = tid >> 6;
  const int row16 = lane & 15, cgrp = lane >> 4;
  const int ntb = blockIdx.x % 36, mtb = blockIdx.x / 36;
  const int sec = ntb / 12;
  const int n0 = ntb * 64;
  const int m0 = mtb * 64;

  f32x4 acc[4] = {zero4(), zero4(), zero4(), zero4()};

  for (int k0 = 0; k0 < 768; k0 += 64) {
    #pragma unroll
    for (int c = 0; c < 2; ++c) {
      int cc = (wv * 2 + c) * 64 + lane;
      int row = cc >> 3, ch = cc & 7, chs = ch ^ (row & 7);
      gload16(ldsA + (wv * 2 + c) * 1024, xb + (size_t)(m0 + row) * 768 + k0 + chs * 8);
      gload16(ldsB + (wv * 2 + c) * 1024, wt + (size_t)(n0 + row) * 768 + k0 + chs * 8);
    }
    __syncthreads();
    if (sec < 2) {
      bf16x8 af[2];
      #pragma unroll
      for (int k2 = 0; k2 < 2; ++k2) af[k2] = frag_ld(ldsA, wv * 16 + row16, k2 * 4 + cgrp);
      #pragma unroll
      for (int nt = 0; nt < 4; ++nt)
        #pragma unroll
        for (int k2 = 0; k2 < 2; ++k2) {
          bf16x8 bf = frag_ld(ldsB, nt * 16 + row16, k2 * 4 + cgrp);
          acc[nt] = mfma_bf16(af[k2], bf, acc[nt]);
        }
    } else {
      bf16x8 af[2];
      #pragma unroll
      for (int k2 = 0; k2 < 2; ++k2) af[k2] = frag_ld(ldsB, wv * 16 + row16, k2 * 4 + cgrp);
      #pragma unroll
      for (int mt = 0; mt < 4; ++mt)
        #pragma unroll
        for (int k2 = 0; k2 < 2; ++k2) {
          bf16x8 bx = frag_ld(ldsA, mt * 16 + row16, k2 * 4 + cgrp);
          acc[mt] = mfma_bf16(af[k2], bx, acc[mt]);
        }
    }
    __syncthreads();
  }

  if (sec < 2) {
    unsigned short* dst = (sec == 0) ? q_ws : k_ws;
    const float* bias = (sec == 0) ? bq : bk;
    int nl0 = (ntb % 12) * 64;
    #pragma unroll
    for (int nt = 0; nt < 4; ++nt) {
      int nn = nl0 + nt * 16 + row16;
      float bb = bias[nn];
      int hh = nn >> 6, dd = nn & 63;
      #pragma unroll
      for (int j = 0; j < 4; ++j) {
        int m = m0 + wv * 16 + cgrp * 4 + j;
        int b_ = m >> 10, s_ = m & 1023;
        dst[(size_t)((b_ * 12 + hh) * 1024 + s_) * 64 + dd] = f2bf(acc[nt][j] + bb);
      }
    }
  } else {
    int nl0 = (ntb % 12) * 64;
    #pragma unroll
    for (int j = 0; j < 4; ++j) {
      int nn = nl0 + wv * 16 + cgrp * 4 + j;
      float bb = bv[nn];
      int hh = nn >> 6, dd = nn & 63;
      #pragma unroll
      for (int mt = 0; mt < 4; ++mt) {
        int m = m0 + mt * 16 + row16;
        int b_ = m >> 10, s_ = m & 1023;
        vt_ws[(size_t)((b_ * 12 + hh) * 64 + dd) * 1024 + s_] = f2bf(acc[mt][j] + bb);
      }
    }
  }
}

// ------------------------- K2: one-shot 64x64 score tile -> unnormalized p
// grid 12288, XCD-chunked. 4 waves, each a 32x32 quadrant. s3 scratch ALIASES
// the dead K/PE staging LDS (kf/pef live in registers after the b2 barrier):
// LDS 51.7 -> 33.3 KB => 4 blocks/CU instead of 3.
__global__ __launch_bounds__(256) void k2_score(
    const unsigned short* __restrict__ q_ws, const unsigned short* __restrict__ k_ws,
    const unsigned short* __restrict__ peb, const float* __restrict__ mask,
    unsigned short* __restrict__ p_out, float* __restrict__ rsum_part) {
  __shared__ __align__(16) char kpe_lds[24576];   // K(8K)+PE(16K); s3t after b2
  __shared__ unsigned short p_sh[64 * 64];        // swizzled p tile, bf16
  __shared__ float rsum_sh[2][64];

  char* k_lds = kpe_lds;
  char* pe_lds = kpe_lds + 8192;

  const int tid = threadIdx.x, lane = tid & 63, wv = tid >> 6;
  const int wl = wv >> 1, wr = wv & 1;
  const int row16 = lane & 15, cgrp = lane >> 4;

  const int bid = blockIdx.x;
  const int swz = (bid & 7) * 1536 + (bid >> 3);   // XCD-chunked (12288 = 8*1536)
  const int rt = swz & 15, lt = (swz >> 4) & 15, bh = swz >> 8;
  const int b = bh / NH;
  const int l0 = lt * 64, r0 = rt * 64;

  const unsigned short* qh = q_ws + (size_t)bh * S * HD;
  const unsigned short* khp = k_ws + (size_t)bh * S * HD;
  const float* maskb = mask + b * S;

  // ---- stage K tile [64][64] and PE window [128][64] (swizzled) ----
  #pragma unroll
  for (int c = 0; c < 2; ++c) {
    int cc = (wv * 2 + c) * 64 + lane;
    int row = cc >> 3, ch = cc & 7, chs = ch ^ (row & 7);
    gload16(k_lds + (wv * 2 + c) * 1024, khp + (size_t)(r0 + row) * HD + chs * 8);
  }
  {
    int m0 = l0 - r0 + 960;  // in [0,1920]
    #pragma unroll
    for (int c = 0; c < 4; ++c) {
      int cc = (wv * 4 + c) * 64 + lane;
      int row = cc >> 3, ch = cc & 7, chs = ch ^ (row & 7);
      gload16(pe_lds + (wv * 4 + c) * 1024, peb + (size_t)(m0 + row) * HD + chs * 8);
    }
  }

  // Q fragments straight from global (overlaps with staging)
  bf16x8 qf[2][2];
  #pragma unroll
  for (int ltl = 0; ltl < 2; ++ltl)
    #pragma unroll
    for (int k2 = 0; k2 < 2; ++k2)
      qf[ltl][k2] = *(const bf16x8*)(qh + (size_t)(l0 + wl * 32 + ltl * 16 + row16) * HD +
                                     k2 * 32 + cgrp * 8);
  __syncthreads();                                 // b1: staging visible

  // ---- fragment reads: K, PE -> registers ----
  bf16x8 kf[2][2], pef[4][2];
  #pragma unroll
  for (int rtl = 0; rtl < 2; ++rtl)
    #pragma unroll
    for (int k2 = 0; k2 < 2; ++k2)
      kf[rtl][k2] = frag_ld(k_lds, wr * 32 + rtl * 16 + row16, k2 * 4 + cgrp);
  const int qb = (wl - wr) * 32 + 32;   // quadrant window base: 0 / 32 / 64
  #pragma unroll
  for (int jt = 0; jt < 4; ++jt)
    #pragma unroll
    for (int k2 = 0; k2 < 2; ++k2)
      pef[jt][k2] = frag_ld(pe_lds, qb + jt * 16 + row16, k2 * 4 + cgrp);
  __syncthreads();                                 // b2: staging LDS now dead

  // s3 scratch aliases the staging region: per-wave [64 jj][36 pad] bf16
  unsigned short* s3w = (unsigned short*)kpe_lds + wv * (64 * 36);

  // ---- S3 = K @ PE^T -> per-wave LDS transposed [jj][r], bf16 ----
  #pragma unroll
  for (int rtl = 0; rtl < 2; ++rtl)
    #pragma unroll
    for (int jt = 0; jt < 4; ++jt) {
      f32x4 a3 = zero4();
      a3 = mfma_bf16(kf[rtl][0], pef[jt][0], a3);
      a3 = mfma_bf16(kf[rtl][1], pef[jt][1], a3);
      us4 o;
      o[0] = f2bf(a3[0]); o[1] = f2bf(a3[1]); o[2] = f2bf(a3[2]); o[3] = f2bf(a3[3]);
      *(us4*)(s3w + (jt * 16 + row16) * 36 + rtl * 16 + cgrp * 4) = o;
    }

  // ---- S1 = Q @ K^T ----
  f32x4 s1[2][2];
  #pragma unroll
  for (int ltl = 0; ltl < 2; ++ltl)
    #pragma unroll
    for (int rtl = 0; rtl < 2; ++rtl) {
      f32x4 a1 = zero4();
      a1 = mfma_bf16(qf[ltl][0], kf[rtl][0], a1);
      a1 = mfma_bf16(qf[ltl][1], kf[rtl][1], a1);
      s1[ltl][rtl] = a1;
    }
  // ---- S2 = Q @ PE^T (registers, gathered via shfl) ----
  f32x4 s2[2][4];
  #pragma unroll
  for (int ltl = 0; ltl < 2; ++ltl)
    #pragma unroll
    for (int jt = 0; jt < 4; ++jt) {
      f32x4 a2 = zero4();
      a2 = mfma_bf16(qf[ltl][0], pef[jt][0], a2);
      a2 = mfma_bf16(qf[ltl][1], pef[jt][1], a2);
      s2[ltl][jt] = a2;
    }

  // ---- combine: diag gathers + exp + p_sh + rowsum partials ----
  float rs[2][4] = {};
  #pragma unroll
  for (int rtl = 0; rtl < 2; ++rtl) {
    float mval = maskb[r0 + wr * 32 + rtl * 16 + row16];
    #pragma unroll
    for (int ltl = 0; ltl < 2; ++ltl) {
      const int jtA = ltl - rtl + 1;
      #pragma unroll
      for (int j = 0; j < 4; ++j) {
        int dl = ltl * 16 + cgrp * 4 + j;
        int dr = rtl * 16 + row16;
        int jjq = dl - dr + 31;                       // [0,62]
        int src = (lane & 48) | (jjq & 15);
        float vA = __shfl(s2[ltl][jtA][j], src, 64);
        float vB = __shfl(s2[ltl][jtA + 1][j], src, 64);
        float b1 = ((jjq >> 4) == jtA) ? vA : vB;
        float b2 = bf2f(s3w[jjq * 36 + dr]);
        float logit = (s1[ltl][rtl][j] + b1 + b2) * 0.125f + mval;
        float p = __expf(logit);
        rs[ltl][j] += p;
        int dlb = wl * 32 + dl, drb = wr * 32 + dr;
        p_sh[dlb * 64 + (drb ^ ((dlb & 7) << 3))] = f2bf(p);
      }
    }
  }

  // ---- rowsum: reduce over the 16 dr lanes -> LDS partials per wr ----
  #pragma unroll
  for (int ltl = 0; ltl < 2; ++ltl)
    #pragma unroll
    for (int j = 0; j < 4; ++j) {
      float v = rs[ltl][j];
      v += __shfl_xor(v, 1, 64);
      v += __shfl_xor(v, 2, 64);
      v += __shfl_xor(v, 4, 64);
      v += __shfl_xor(v, 8, 64);
      rs[ltl][j] = v;
    }
  if (row16 == 0) {
    #pragma unroll
    for (int ltl = 0; ltl < 2; ++ltl)
      #pragma unroll
      for (int j = 0; j < 4; ++j)
        rsum_sh[wr][wl * 32 + ltl * 16 + cgrp * 4 + j] = rs[ltl][j];
  }
  __syncthreads();                                 // b3: p_sh + rsum_sh ready

  // one f32 per row per block -> [bh*16+lt][row][rt]
  if (tid < 64)
    rsum_part[((size_t)(bh * 16 + lt) * 64 + tid) * 16 + rt] =
        rsum_sh[0][tid] + rsum_sh[1][tid];

  // ---- coalesced p tile write-out ----
  #pragma unroll
  for (int p2 = 0; p2 < 2; ++p2) {
    int id = p2 * 256 + tid, dl = id >> 3, c = id & 7;
    uint4 w = *(const uint4*)((const char*)p_sh + dl * 128 + (c ^ (dl & 7)) * 16);
    *(uint4*)(p_out + ((size_t)bh * S + l0 + dl) * S + r0 + c * 8) = w;
  }
}

// -------- K3: normalize probs (f32) + partial PV GEMM over 4 rt tiles
// grid: 3072 blocks, XCD-chunked; double-buffered p tile in LDS.
// ctx partials (unnormalized) -> ctx_part[rq]; rq==0 persists inv to inv_ws.
__global__ __launch_bounds__(256) void k3_pv(
    const unsigned short* __restrict__ p_in, const unsigned short* __restrict__ vt_ws,
    const float* __restrict__ rsum_part, float* __restrict__ ctx_part,
    float* __restrict__ inv_ws, float* __restrict__ out_probs) {
  __shared__ char p_sh[2][8192];
  __shared__ float inv_sh[64];

  const int tid = threadIdx.x, lane = tid & 63, wv = tid >> 6;
  const int row16 = lane & 15, cgrp = lane >> 4;
  const int bid = blockIdx.x;
  const int swz = (bid & 7) * 384 + (bid >> 3);   // XCD-chunked (3072 = 8*384)
  const int rq = swz & 3, lt = (swz >> 2) & 15, bh = swz >> 6;
  const int l0 = lt * 64, rbase = rq * 256;

  const unsigned short* vth = vt_ws + (size_t)bh * HD * S;
  float* probs_bh = out_probs + (size_t)bh * S * S;

  if (tid < 64) {
    const float4* pp =
        (const float4*)(rsum_part + ((size_t)(bh * 16 + lt) * 64 + tid) * 16);
    float s = 0.f;
    #pragma unroll
    for (int i = 0; i < 4; ++i) {
      float4 v = pp[i];
      s += v.x + v.y + v.z + v.w;
    }
    float iv = 1.0f / s;
    inv_sh[tid] = iv;
    if (rq == 0) inv_ws[bh * S + l0 + tid] = iv;
  }

  auto stage = [&](char* buf, int r0) {
    #pragma unroll
    for (int c = 0; c < 2; ++c) {
      int cc = (wv * 2 + c) * 64 + lane;
      int row = cc >> 3, ch = cc & 7, chs = ch ^ (row & 7);
      gload16(buf + (wv * 2 + c) * 1024,
              p_in + ((size_t)bh * S + l0 + row) * S + r0 + chs * 8);
    }
  };

  stage(p_sh[0], rbase);
  __syncthreads();

  f32x4 ctxacc[4] = {zero4(), zero4(), zero4(), zero4()};

  for (int it = 0; it < 4; ++it) {
    const int r0 = rbase + it * 64, cur = it & 1;
    if (it < 3) stage(p_sh[cur ^ 1], r0 + 64);
    const char* cb = p_sh[cur];

    // normalized probs write (coalesced)
    #pragma unroll
    for (int p2 = 0; p2 < 2; ++p2) {
      int id = p2 * 256 + tid, dl = id >> 3, c = id & 7;
      uint4 w = *(const uint4*)(cb + dl * 128 + (c ^ (dl & 7)) * 16);
      const unsigned short* pu = (const unsigned short*)&w;
      float iv = inv_sh[dl];
      float* dst = probs_bh + (size_t)(l0 + dl) * S + r0 + c * 8;
      float4 lo{bf2f(pu[0]) * iv, bf2f(pu[1]) * iv, bf2f(pu[2]) * iv, bf2f(pu[3]) * iv};
      float4 hi{bf2f(pu[4]) * iv, bf2f(pu[5]) * iv, bf2f(pu[6]) * iv, bf2f(pu[7]) * iv};
      *(float4*)dst = lo; *(float4*)(dst + 4) = hi;
    }

    // PV accumulate (unnormalized p)
    {
      int lrow = wv * 16 + row16;
      bf16x8 pa[2];
      #pragma unroll
      for (int kc = 0; kc < 2; ++kc) {
        int ch = kc * 4 + cgrp, chs = ch ^ (lrow & 7);
        pa[kc] = *(const bf16x8*)(cb + lrow * 128 + chs * 16);
      }
      #pragma unroll
      for (int dt = 0; dt < 4; ++dt) {
        bf16x8 vb0 = *(const bf16x8*)(vth + (size_t)(dt * 16 + row16) * S + r0 + cgrp * 8);
        bf16x8 vb1 = *(const bf16x8*)(vth + (size_t)(dt * 16 + row16) * S + r0 + 32 + cgrp * 8);
        ctxacc[dt] = mfma_bf16(pa[0], vb0, ctxacc[dt]);
        ctxacc[dt] = mfma_bf16(pa[1], vb1, ctxacc[dt]);
      }
    }
    __syncthreads();
  }

  // unnormalized ctx partial: [rq][bh][l][d]
  #pragma unroll
  for (int dt = 0; dt < 4; ++dt)
    #pragma unroll
    for (int j = 0; j < 4; ++j) {
      int lr = wv * 16 + cgrp * 4 + j;
      ctx_part[((size_t)(rq * 48 + bh) * S + l0 + lr) * 64 + dt * 16 + row16] =
          ctxacc[dt][j];
    }
}

// -------- K4: ctx = inv * sum_rq ctx_part  (streaming reduce)
// grid 1536 * 256 threads = 393216 = 48*1024*64/8 elems at 8 f32/thread.
__global__ __launch_bounds__(256) void k4_red(
    const float* __restrict__ ctx_part, const float* __restrict__ inv_ws,
    float* __restrict__ out_ctx) {
  int gid = blockIdx.x * 256 + threadIdx.x;     // 0..393215
  int t = gid >> 3, d0 = (gid & 7) * 8;         // token (bh*1024+l), d offset
  int bh = t >> 10, l = t & 1023;
  float4 s0{0.f, 0.f, 0.f, 0.f}, s1{0.f, 0.f, 0.f, 0.f};
  #pragma unroll
  for (int rq = 0; rq < 4; ++rq) {
    const float* p = ctx_part + ((size_t)(rq * 48 + bh) * S + l) * 64 + d0;
    float4 a = *(const float4*)p;
    float4 b = *(const float4*)(p + 4);
    s0.x += a.x; s0.y += a.y; s0.z += a.z; s0.w += a.w;
    s1.x += b.x; s1.y += b.y; s1.z += b.z; s1.w += b.w;
  }
  float iv = inv_ws[t];
  s0.x *= iv; s0.y *= iv; s0.z *= iv; s0.w *= iv;
  s1.x *= iv; s1.y *= iv; s1.z *= iv; s1.w *= iv;
  int b_ = bh / NH, h = bh % NH;
  float* dst = out_ctx + ((size_t)(b_ * S + l)) * HID + h * HD + d0;
  *(float4*)dst = s0;
  *(float4*)(dst + 4) = s1;
}

}  // namespace

extern "C" void kernel_launch(void* const* d_in, const int* in_sizes, int n_in,
                              void* d_out, int out_size, void* d_ws, size_t ws_size,
                              hipStream_t stream) {
  const float* hidden = (const float*)d_in[0];
  const float* mask   = (const float*)d_in[1];
  const float* Wq = (const float*)d_in[2];
  const float* bq = (const float*)d_in[3];
  const float* Wk = (const float*)d_in[4];
  const float* bk = (const float*)d_in[5];
  const float* Wv = (const float*)d_in[6];
  const float* bv = (const float*)d_in[7];
  const float* de = (const float*)d_in[8];

  unsigned short* ws = (unsigned short*)d_ws;
  unsigned short* q_ws  = ws;                        // 48*1024*64
  unsigned short* k_ws  = ws + 3145728;
  unsigned short* vt_ws = ws + 6291456;              // [bh][d][s]
  unsigned short* xb    = ws + 9437184;              // [4096][768]
  unsigned short* wt    = ws + 12582912;             // [2304][768]
  unsigned short* peb   = ws + 14352384;             // [2048][64]
  float* rsum_part = (float*)(ws + 14483456);        // [768][64][16] f32
  unsigned short* p_ws  = ws + 16056320;             // [bh][l][r] bf16, 96MB
  float* ctx_part = (float*)(ws + 66387968);         // [4][48][1024][64] f32
  float* inv_ws   = (float*)(ws + 91553792);         // [48*1024] f32
  // end = 91652096 shorts = 183.3 MB (ws ~816 MB per poison-fill size)

  float* outc = (float*)d_out;
  float* outp = outc + (size_t)4 * 1024 * 768;

  hipLaunchKernelGGL(k0_cvt_x, dim3(1536), dim3(256), 0, stream, hidden, xb);
  hipLaunchKernelGGL(k0_cvt_pe, dim3(64), dim3(256), 0, stream, de, peb);
  hipLaunchKernelGGL(k0_wt, dim3(432), dim3(256), 0, stream, Wq, Wk, Wv, wt);
  hipLaunchKernelGGL(k1_qkv, dim3(2304), dim3(256), 0, stream,
                     xb, wt, bq, bk, bv, q_ws, k_ws, vt_ws);
  hipLaunchKernelGGL(k2_score, dim3(12288), dim3(256), 0, stream,
                     q_ws, k_ws, peb, mask, p_ws, rsum_part);
  hipLaunchKernelGGL(k3_pv, dim3(3072), dim3(256), 0, stream,
                     p_ws, vt_ws, rsum_part, ctx_part, inv_ws, outp);
  hipLaunchKernelGGL(k4_red, dim3(1536), dim3(256), 0, stream,
                     ctx_part, inv_ws, outc);
}

// Round 12
// 206.685 us; speedup vs baseline: 2.0065x; 1.1140x over previous
//
#include <hip/hip_runtime.h>
#include <hip/hip_bf16.h>

#define DEVFN __device__ __forceinline__

typedef __bf16 bf16x8 __attribute__((ext_vector_type(8)));
typedef float f32x4 __attribute__((ext_vector_type(4)));
typedef unsigned short ushort8 __attribute__((ext_vector_type(8)));
typedef unsigned short us4 __attribute__((ext_vector_type(4)));

namespace {

constexpr int S = 1024;
constexpr int HID = 768;
constexpr int NH = 12;
constexpr int HD = 64;

DEVFN unsigned short f2bf(float f) {
  union { float f; unsigned u; } v; v.f = f;
  unsigned r = v.u + 0x7FFF + ((v.u >> 16) & 1);   // RNE
  return (unsigned short)(r >> 16);
}

DEVFN float bf2f(unsigned short u) {
  union { unsigned u; float f; } v; v.u = ((unsigned)u) << 16; return v.f;
}

DEVFN f32x4 zero4() { return f32x4{0.f, 0.f, 0.f, 0.f}; }

DEVFN f32x4 mfma_bf16(bf16x8 a, bf16x8 b, f32x4 c) {
  return __builtin_amdgcn_mfma_f32_16x16x32_bf16(a, b, c, 0, 0, 0);
}

// async global->LDS, 16B per lane; dest = lds_base + lane*16 (wave-uniform base)
DEVFN void gload16(void* lds_base, const void* gsrc) {
  __builtin_amdgcn_global_load_lds(
      (const __attribute__((address_space(1))) void*)gsrc,
      (__attribute__((address_space(3))) void*)lds_base, 16, 0, 0);
}

// read one MFMA fragment (8 contiguous bf16) from a [rows][64] bf16 LDS tile
// stored with chunk-XOR swizzle: LDS[row][ch] = G[row][ch ^ (row&7)]
DEVFN bf16x8 frag_ld(const char* tile, int row, int ch) {
  int chs = ch ^ (row & 7);
  return *(const bf16x8*)(tile + row * 128 + chs * 16);
}

// ---------------------------------------------------------------- K0: preps
__global__ void k0_cvt_x(const float* __restrict__ x, unsigned short* __restrict__ xb) {
  size_t i = (size_t)(blockIdx.x * 256 + threadIdx.x) * 8;
  float4 a = *(const float4*)(x + i);
  float4 c = *(const float4*)(x + i + 4);
  ushort8 o;
  o[0] = f2bf(a.x); o[1] = f2bf(a.y); o[2] = f2bf(a.z); o[3] = f2bf(a.w);
  o[4] = f2bf(c.x); o[5] = f2bf(c.y); o[6] = f2bf(c.z); o[7] = f2bf(c.w);
  *(ushort8*)(xb + i) = o;
}

// dist_emb [2047][64] f32 -> [2048][64] bf16 (row 2047 zero-padded)
__global__ void k0_cvt_pe(const float* __restrict__ de, unsigned short* __restrict__ peb) {
  size_t i = (size_t)(blockIdx.x * 256 + threadIdx.x) * 8;
  int row = (int)(i >> 6);
  ushort8 o;
  if (row < 2047) {
    float4 a = *(const float4*)(de + i);
    float4 c = *(const float4*)(de + i + 4);
    o[0] = f2bf(a.x); o[1] = f2bf(a.y); o[2] = f2bf(a.z); o[3] = f2bf(a.w);
    o[4] = f2bf(c.x); o[5] = f2bf(c.y); o[6] = f2bf(c.z); o[7] = f2bf(c.w);
  } else {
    o = ushort8{0, 0, 0, 0, 0, 0, 0, 0};
  }
  *(ushort8*)(peb + i) = o;
}

// W[k][n] f32 -> wt[sec*768+n][k] bf16  (64x64 LDS tile transpose)
__global__ __launch_bounds__(256) void k0_wt(const float* __restrict__ Wq,
                                             const float* __restrict__ Wk,
                                             const float* __restrict__ Wv,
                                             unsigned short* __restrict__ wt) {
  __shared__ float t[64][65];
  int bidx = blockIdx.x;                 // 3 * 12 * 12 = 432
  int sec = bidx / 144, rem = bidx % 144;
  int ktb = rem / 12, ntb = rem % 12;
  const float* W = (sec == 0) ? Wq : ((sec == 1) ? Wk : Wv);
  int k0 = ktb * 64, n0 = ntb * 64;
  int tid = threadIdx.x;
  #pragma unroll
  for (int p = 0; p < 4; ++p) {
    int id = p * 256 + tid;              // 0..1023
    int row = id >> 4, ch = id & 15;
    float4 v = *(const float4*)(W + (size_t)(k0 + row) * 768 + n0 + ch * 4);
    t[row][ch * 4 + 0] = v.x; t[row][ch * 4 + 1] = v.y;
    t[row][ch * 4 + 2] = v.z; t[row][ch * 4 + 3] = v.w;
  }
  __syncthreads();
  #pragma unroll
  for (int p = 0; p < 2; ++p) {
    int id = p * 256 + tid;              // 0..511
    int nrow = id >> 3, c8 = id & 7;
    ushort8 o;
    #pragma unroll
    for (int i = 0; i < 8; ++i) o[i] = f2bf(t[c8 * 8 + i][nrow]);
    *(ushort8*)(wt + (size_t)(sec * 768 + n0 + nrow) * 768 + k0 + c8 * 8) = o;
  }
}

// ------------------------------------------------- K1: fused QKV projection
// (proven 64x64-tile version)
__global__ __launch_bounds__(256) void k1_qkv(
    const unsigned short* __restrict__ xb, const unsigned short* __restrict__ wt,
    const float* __restrict__ bq, const float* __restrict__ bk, const float* __restrict__ bv,
    unsigned short* __restrict__ q_ws, unsigned short* __restrict__ k_ws,
    unsigned short* __restrict__ vt_ws) {
  __shared__ char ldsA[8192], ldsB[8192];
  const int tid = threadIdx.x, lane = tid & 63, wv = tid >> 6;
  const int row16 = lane & 15, cgrp = lane >> 4;
  const int ntb = blockIdx.x % 36, mtb = blockIdx.x / 36;
  const int sec = ntb / 12;
  const int n0 = ntb * 64;
  const int m0 = mtb * 64;

  f32x4 acc[4] = {zero4(), zero4(), zero4(), zero4()};

  for (int k0 = 0; k0 < 768; k0 += 64) {
    #pragma unroll
    for (int c = 0; c < 2; ++c) {
      int cc = (wv * 2 + c) * 64 + lane;
      int row = cc >> 3, ch = cc & 7, chs = ch ^ (row & 7);
      gload16(ldsA + (wv * 2 + c) * 1024, xb + (size_t)(m0 + row) * 768 + k0 + chs * 8);
      gload16(ldsB + (wv * 2 + c) * 1024, wt + (size_t)(n0 + row) * 768 + k0 + chs * 8);
    }
    __syncthreads();
    if (sec < 2) {
      bf16x8 af[2];
      #pragma unroll
      for (int k2 = 0; k2 < 2; ++k2) af[k2] = frag_ld(ldsA, wv * 16 + row16, k2 * 4 + cgrp);
      #pragma unroll
      for (int nt = 0; nt < 4; ++nt)
        #pragma unroll
        for (int k2 = 0; k2 < 2; ++k2) {
          bf16x8 bf = frag_ld(ldsB, nt * 16 + row16, k2 * 4 + cgrp);
          acc[nt] = mfma_bf16(af[k2], bf, acc[nt]);
        }
    } else {
      bf16x8 af[2];
      #pragma unroll
      for (int k2 = 0; k2 < 2; ++k2) af[k2] = frag_ld(ldsB, wv * 16 + row16, k2 * 4 + cgrp);
      #pragma unroll
      for (int mt = 0; mt < 4; ++mt)
        #pragma unroll
        for (int k2 = 0; k2 < 2; ++k2) {
          bf16x8 bx = frag_ld(ldsA, mt * 16 + row16, k2 * 4 + cgrp);
          acc[mt] = mfma_bf16(af[k2], bx, acc[mt]);
        }
    }
    __syncthreads();
  }

  if (sec < 2) {
    unsigned short* dst = (sec == 0) ? q_ws : k_ws;
    const float* bias = (sec == 0) ? bq : bk;
    int nl0 = (ntb % 12) * 64;
    #pragma unroll
    for (int nt = 0; nt < 4; ++nt) {
      int nn = nl0 + nt * 16 + row16;
      float bb = bias[nn];
      int hh = nn >> 6, dd = nn & 63;
      #pragma unroll
      for (int j = 0; j < 4; ++j) {
        int m = m0 + wv * 16 + cgrp * 4 + j;
        int b_ = m >> 10, s_ = m & 1023;
        dst[(size_t)((b_ * 12 + hh) * 1024 + s_) * 64 + dd] = f2bf(acc[nt][j] + bb);
      }
    }
  } else {
    int nl0 = (ntb % 12) * 64;
    #pragma unroll
    for (int j = 0; j < 4; ++j) {
      int nn = nl0 + wv * 16 + cgrp * 4 + j;
      float bb = bv[nn];
      int hh = nn >> 6, dd = nn & 63;
      #pragma unroll
      for (int mt = 0; mt < 4; ++mt) {
        int m = m0 + mt * 16 + row16;
        int b_ = m >> 10, s_ = m & 1023;
        vt_ws[(size_t)((b_ * 12 + hh) * 64 + dd) * 1024 + s_] = f2bf(acc[mt][j] + bb);
      }
    }
  }
}

// ------------------------- K2: one-shot 64x64 score tile -> unnormalized p
// grid 12288, XCD-chunked. 4 waves, each a 32x32 quadrant. s3 scratch ALIASES
// the dead K/PE staging LDS (kf/pef live in registers after the b2 barrier):
// LDS 33.3 KB => 4 blocks/CU.
__global__ __launch_bounds__(256) void k2_score(
    const unsigned short* __restrict__ q_ws, const unsigned short* __restrict__ k_ws,
    const unsigned short* __restrict__ peb, const float* __restrict__ mask,
    unsigned short* __restrict__ p_out, float* __restrict__ rsum_part) {
  __shared__ __align__(16) char kpe_lds[24576];   // K(8K)+PE(16K); s3t after b2
  __shared__ unsigned short p_sh[64 * 64];        // swizzled p tile, bf16
  __shared__ float rsum_sh[2][64];

  char* k_lds = kpe_lds;
  char* pe_lds = kpe_lds + 8192;

  const int tid = threadIdx.x, lane = tid & 63, wv = tid >> 6;
  const int wl = wv >> 1, wr = wv & 1;
  const int row16 = lane & 15, cgrp = lane >> 4;

  const int bid = blockIdx.x;
  const int swz = (bid & 7) * 1536 + (bid >> 3);   // XCD-chunked (12288 = 8*1536)
  const int rt = swz & 15, lt = (swz >> 4) & 15, bh = swz >> 8;
  const int b = bh / NH;
  const int l0 = lt * 64, r0 = rt * 64;

  const unsigned short* qh = q_ws + (size_t)bh * S * HD;
  const unsigned short* khp = k_ws + (size_t)bh * S * HD;
  const float* maskb = mask + b * S;

  // ---- stage K tile [64][64] and PE window [128][64] (swizzled) ----
  #pragma unroll
  for (int c = 0; c < 2; ++c) {
    int cc = (wv * 2 + c) * 64 + lane;
    int row = cc >> 3, ch = cc & 7, chs = ch ^ (row & 7);
    gload16(k_lds + (wv * 2 + c) * 1024, khp + (size_t)(r0 + row) * HD + chs * 8);
  }
  {
    int m0 = l0 - r0 + 960;  // in [0,1920]
    #pragma unroll
    for (int c = 0; c < 4; ++c) {
      int cc = (wv * 4 + c) * 64 + lane;
      int row = cc >> 3, ch = cc & 7, chs = ch ^ (row & 7);
      gload16(pe_lds + (wv * 4 + c) * 1024, peb + (size_t)(m0 + row) * HD + chs * 8);
    }
  }

  // Q fragments straight from global (overlaps with staging)
  bf16x8 qf[2][2];
  #pragma unroll
  for (int ltl = 0; ltl < 2; ++ltl)
    #pragma unroll
    for (int k2 = 0; k2 < 2; ++k2)
      qf[ltl][k2] = *(const bf16x8*)(qh + (size_t)(l0 + wl * 32 + ltl * 16 + row16) * HD +
                                     k2 * 32 + cgrp * 8);
  __syncthreads();                                 // b1: staging visible

  // ---- fragment reads: K, PE -> registers ----
  bf16x8 kf[2][2], pef[4][2];
  #pragma unroll
  for (int rtl = 0; rtl < 2; ++rtl)
    #pragma unroll
    for (int k2 = 0; k2 < 2; ++k2)
      kf[rtl][k2] = frag_ld(k_lds, wr * 32 + rtl * 16 + row16, k2 * 4 + cgrp);
  const int qb = (wl - wr) * 32 + 32;   // quadrant window base: 0 / 32 / 64
  #pragma unroll
  for (int jt = 0; jt < 4; ++jt)
    #pragma unroll
    for (int k2 = 0; k2 < 2; ++k2)
      pef[jt][k2] = frag_ld(pe_lds, qb + jt * 16 + row16, k2 * 4 + cgrp);
  __syncthreads();                                 // b2: staging LDS now dead

  // s3 scratch aliases the staging region: per-wave [64 jj][36 pad] bf16
  unsigned short* s3w = (unsigned short*)kpe_lds + wv * (64 * 36);

  // ---- S3 = K @ PE^T -> per-wave LDS transposed [jj][r], bf16 ----
  #pragma unroll
  for (int rtl = 0; rtl < 2; ++rtl)
    #pragma unroll
    for (int jt = 0; jt < 4; ++jt) {
      f32x4 a3 = zero4();
      a3 = mfma_bf16(kf[rtl][0], pef[jt][0], a3);
      a3 = mfma_bf16(kf[rtl][1], pef[jt][1], a3);
      us4 o;
      o[0] = f2bf(a3[0]); o[1] = f2bf(a3[1]); o[2] = f2bf(a3[2]); o[3] = f2bf(a3[3]);
      *(us4*)(s3w + (jt * 16 + row16) * 36 + rtl * 16 + cgrp * 4) = o;
    }

  // ---- S1 = Q @ K^T ----
  f32x4 s1[2][2];
  #pragma unroll
  for (int ltl = 0; ltl < 2; ++ltl)
    #pragma unroll
    for (int rtl = 0; rtl < 2; ++rtl) {
      f32x4 a1 = zero4();
      a1 = mfma_bf16(qf[ltl][0], kf[rtl][0], a1);
      a1 = mfma_bf16(qf[ltl][1], kf[rtl][1], a1);
      s1[ltl][rtl] = a1;
    }
  // ---- S2 = Q @ PE^T (registers, gathered via shfl) ----
  f32x4 s2[2][4];
  #pragma unroll
  for (int ltl = 0; ltl < 2; ++ltl)
    #pragma unroll
    for (int jt = 0; jt < 4; ++jt) {
      f32x4 a2 = zero4();
      a2 = mfma_bf16(qf[ltl][0], pef[jt][0], a2);
      a2 = mfma_bf16(qf[ltl][1], pef[jt][1], a2);
      s2[ltl][jt] = a2;
    }

  // ---- combine: diag gathers + exp + p_sh + rowsum partials ----
  float rs[2][4] = {};
  #pragma unroll
  for (int rtl = 0; rtl < 2; ++rtl) {
    float mval = maskb[r0 + wr * 32 + rtl * 16 + row16];
    #pragma unroll
    for (int ltl = 0; ltl < 2; ++ltl) {
      const int jtA = ltl - rtl + 1;
      #pragma unroll
      for (int j = 0; j < 4; ++j) {
        int dl = ltl * 16 + cgrp * 4 + j;
        int dr = rtl * 16 + row16;
        int jjq = dl - dr + 31;                       // [0,62]
        int src = (lane & 48) | (jjq & 15);
        float vA = __shfl(s2[ltl][jtA][j], src, 64);
        float vB = __shfl(s2[ltl][jtA + 1][j], src, 64);
        float b1 = ((jjq >> 4) == jtA) ? vA : vB;
        float b2 = bf2f(s3w[jjq * 36 + dr]);
        float logit = (s1[ltl][rtl][j] + b1 + b2) * 0.125f + mval;
        float p = __expf(logit);
        rs[ltl][j] += p;
        int dlb = wl * 32 + dl, drb = wr * 32 + dr;
        p_sh[dlb * 64 + (drb ^ ((dlb & 7) << 3))] = f2bf(p);
      }
    }
  }

  // ---- rowsum: reduce over the 16 dr lanes -> LDS partials per wr ----
  #pragma unroll
  for (int ltl = 0; ltl < 2; ++ltl)
    #pragma unroll
    for (int j = 0; j < 4; ++j) {
      float v = rs[ltl][j];
      v += __shfl_xor(v, 1, 64);
      v += __shfl_xor(v, 2, 64);
      v += __shfl_xor(v, 4, 64);
      v += __shfl_xor(v, 8, 64);
      rs[ltl][j] = v;
    }
  if (row16 == 0) {
    #pragma unroll
    for (int ltl = 0; ltl < 2; ++ltl)
      #pragma unroll
      for (int j = 0; j < 4; ++j)
        rsum_sh[wr][wl * 32 + ltl * 16 + cgrp * 4 + j] = rs[ltl][j];
  }
  __syncthreads();                                 // b3: p_sh + rsum_sh ready

  // one f32 per row per block -> [bh*16+lt][row][rt]
  if (tid < 64)
    rsum_part[((size_t)(bh * 16 + lt) * 64 + tid) * 16 + rt] =
        rsum_sh[0][tid] + rsum_sh[1][tid];

  // ---- coalesced p tile write-out ----
  #pragma unroll
  for (int p2 = 0; p2 < 2; ++p2) {
    int id = p2 * 256 + tid, dl = id >> 3, c = id & 7;
    uint4 w = *(const uint4*)((const char*)p_sh + dl * 128 + (c ^ (dl & 7)) * 16);
    *(uint4*)(p_out + ((size_t)bh * S + l0 + dl) * S + r0 + c * 8) = w;
  }
}

// ---------------- K3: normalize probs (write f32) + PV GEMM + ctx epilogue
// grid: 768 blocks (8x96 XCD-chunked: 16 same-bh blocks share V on one XCD);
// double-buffered p tile in LDS; direct ctx write (R7-proven form).
__global__ __launch_bounds__(256) void k3_pv(
    const unsigned short* __restrict__ p_in, const unsigned short* __restrict__ vt_ws,
    const float* __restrict__ rsum_part, float* __restrict__ out_ctx,
    float* __restrict__ out_probs) {
  __shared__ char p_sh[2][8192];
  __shared__ float inv_sh[64];

  const int tid = threadIdx.x, lane = tid & 63, wv = tid >> 6;
  const int row16 = lane & 15, cgrp = lane >> 4;
  const int bid = blockIdx.x;
  const int swz = (bid & 7) * 96 + (bid >> 3);    // XCD-chunked (768 = 8*96)
  const int lt = swz & 15, bh = swz >> 4;
  const int b = bh / NH, h = bh % NH;
  const int l0 = lt * 64;

  const unsigned short* vth = vt_ws + (size_t)bh * HD * S;
  float* probs_bh = out_probs + (size_t)bh * S * S;

  if (tid < 64) {
    const float4* pp =
        (const float4*)(rsum_part + ((size_t)(bh * 16 + lt) * 64 + tid) * 16);
    float s = 0.f;
    #pragma unroll
    for (int i = 0; i < 4; ++i) {
      float4 v = pp[i];
      s += v.x + v.y + v.z + v.w;
    }
    inv_sh[tid] = 1.0f / s;
  }

  auto stage = [&](char* buf, int r0) {
    #pragma unroll
    for (int c = 0; c < 2; ++c) {
      int cc = (wv * 2 + c) * 64 + lane;
      int row = cc >> 3, ch = cc & 7, chs = ch ^ (row & 7);
      gload16(buf + (wv * 2 + c) * 1024,
              p_in + ((size_t)bh * S + l0 + row) * S + r0 + chs * 8);
    }
  };

  stage(p_sh[0], 0);
  __syncthreads();

  f32x4 ctxacc[4] = {zero4(), zero4(), zero4(), zero4()};

  for (int rt = 0; rt < 16; ++rt) {
    const int r0 = rt * 64, cur = rt & 1;
    if (rt < 15) stage(p_sh[cur ^ 1], r0 + 64);
    const char* cb = p_sh[cur];

    // normalized probs write (coalesced)
    #pragma unroll
    for (int p2 = 0; p2 < 2; ++p2) {
      int id = p2 * 256 + tid, dl = id >> 3, c = id & 7;
      uint4 w = *(const uint4*)(cb + dl * 128 + (c ^ (dl & 7)) * 16);
      const unsigned short* pu = (const unsigned short*)&w;
      float iv = inv_sh[dl];
      float* dst = probs_bh + (size_t)(l0 + dl) * S + r0 + c * 8;
      float4 lo{bf2f(pu[0]) * iv, bf2f(pu[1]) * iv, bf2f(pu[2]) * iv, bf2f(pu[3]) * iv};
      float4 hi{bf2f(pu[4]) * iv, bf2f(pu[5]) * iv, bf2f(pu[6]) * iv, bf2f(pu[7]) * iv};
      *(float4*)dst = lo; *(float4*)(dst + 4) = hi;
    }

    // PV accumulate (unnormalized p; ctx scaled at epilogue)
    {
      int lrow = wv * 16 + row16;
      bf16x8 pa[2];
      #pragma unroll
      for (int kc = 0; kc < 2; ++kc) {
        int ch = kc * 4 + cgrp, chs = ch ^ (lrow & 7);
        pa[kc] = *(const bf16x8*)(cb + lrow * 128 + chs * 16);
      }
      #pragma unroll
      for (int dt = 0; dt < 4; ++dt) {
        bf16x8 vb0 = *(const bf16x8*)(vth + (size_t)(dt * 16 + row16) * S + r0 + cgrp * 8);
        bf16x8 vb1 = *(const bf16x8*)(vth + (size_t)(dt * 16 + row16) * S + r0 + 32 + cgrp * 8);
        ctxacc[dt] = mfma_bf16(pa[0], vb0, ctxacc[dt]);
        ctxacc[dt] = mfma_bf16(pa[1], vb1, ctxacc[dt]);
      }
    }
    __syncthreads();
  }

  #pragma unroll
  for (int dt = 0; dt < 4; ++dt)
    #pragma unroll
    for (int j = 0; j < 4; ++j) {
      int lr = wv * 16 + cgrp * 4 + j;
      out_ctx[((size_t)(b * S + l0 + lr)) * HID + h * HD + dt * 16 + row16] =
          ctxacc[dt][j] * inv_sh[lr];
    }
}

}  // namespace

extern "C" void kernel_launch(void* const* d_in, const int* in_sizes, int n_in,
                              void* d_out, int out_size, void* d_ws, size_t ws_size,
                              hipStream_t stream) {
  const float* hidden = (const float*)d_in[0];
  const float* mask   = (const float*)d_in[1];
  const float* Wq = (const float*)d_in[2];
  const float* bq = (const float*)d_in[3];
  const float* Wk = (const float*)d_in[4];
  const float* bk = (const float*)d_in[5];
  const float* Wv = (const float*)d_in[6];
  const float* bv = (const float*)d_in[7];
  const float* de = (const float*)d_in[8];

  unsigned short* ws = (unsigned short*)d_ws;
  unsigned short* q_ws  = ws;                        // 48*1024*64
  unsigned short* k_ws  = ws + 3145728;
  unsigned short* vt_ws = ws + 6291456;              // [bh][d][s]
  unsigned short* xb    = ws + 9437184;              // [4096][768]
  unsigned short* wt    = ws + 12582912;             // [2304][768]
  unsigned short* peb   = ws + 14352384;             // [2048][64]
  float* rsum_part = (float*)(ws + 14483456);        // [768][64][16] f32
  unsigned short* p_ws  = ws + 16056320;             // [bh][l][r] bf16, 96MB
  // end = 66387968 shorts = 132.8 MB (ws ~816 MB per poison-fill size)

  float* outc = (float*)d_out;
  float* outp = outc + (size_t)4 * 1024 * 768;

  hipLaunchKernelGGL(k0_cvt_x, dim3(1536), dim3(256), 0, stream, hidden, xb);
  hipLaunchKernelGGL(k0_cvt_pe, dim3(64), dim3(256), 0, stream, de, peb);
  hipLaunchKernelGGL(k0_wt, dim3(432), dim3(256), 0, stream, Wq, Wk, Wv, wt);
  hipLaunchKernelGGL(k1_qkv, dim3(2304), dim3(256), 0, stream,
                     xb, wt, bq, bk, bv, q_ws, k_ws, vt_ws);
  hipLaunchKernelGGL(k2_score, dim3(12288), dim3(256), 0, stream,
                     q_ws, k_ws, peb, mask, p_ws, rsum_part);
  hipLaunchKernelGGL(k3_pv, dim3(768), dim3(256), 0, stream,
                     p_ws, vt_ws, rsum_part, outc, outp);
}

// Round 13
// 200.349 us; speedup vs baseline: 2.0700x; 1.0316x over previous
//
#include <hip/hip_runtime.h>
#include <hip/hip_bf16.h>

#define DEVFN __device__ __forceinline__

typedef __bf16 bf16x8 __attribute__((ext_vector_type(8)));
typedef float f32x4 __attribute__((ext_vector_type(4)));
typedef unsigned short ushort8 __attribute__((ext_vector_type(8)));
typedef unsigned short us4 __attribute__((ext_vector_type(4)));

namespace {

constexpr int S = 1024;
constexpr int HID = 768;
constexpr int NH = 12;
constexpr int HD = 64;
// sqrt(0.125 * log2(e)): Q,K,PE pre-scaled so p = exp2(S1+S2+S3+mask*log2e)
constexpr float SC = 0.4246609f;
constexpr float LOG2E = 1.44269504f;

DEVFN unsigned short f2bf(float f) {
  union { float f; unsigned u; } v; v.f = f;
  unsigned r = v.u + 0x7FFF + ((v.u >> 16) & 1);   // RNE
  return (unsigned short)(r >> 16);
}

DEVFN float bf2f(unsigned short u) {
  union { unsigned u; float f; } v; v.u = ((unsigned)u) << 16; return v.f;
}

DEVFN f32x4 zero4() { return f32x4{0.f, 0.f, 0.f, 0.f}; }

DEVFN f32x4 mfma_bf16(bf16x8 a, bf16x8 b, f32x4 c) {
  return __builtin_amdgcn_mfma_f32_16x16x32_bf16(a, b, c, 0, 0, 0);
}

// async global->LDS, 16B per lane; dest = lds_base + lane*16 (wave-uniform base)
DEVFN void gload16(void* lds_base, const void* gsrc) {
  __builtin_amdgcn_global_load_lds(
      (const __attribute__((address_space(1))) void*)gsrc,
      (__attribute__((address_space(3))) void*)lds_base, 16, 0, 0);
}

// read one MFMA fragment (8 contiguous bf16) from a [rows][64] bf16 LDS tile
// stored with chunk-XOR swizzle: LDS[row][ch] = G[row][ch ^ (row&7)]
DEVFN bf16x8 frag_ld(const char* tile, int row, int ch) {
  int chs = ch ^ (row & 7);
  return *(const bf16x8*)(tile + row * 128 + chs * 16);
}

// ---------------------------------------------------------------- K0: preps
__global__ void k0_cvt_x(const float* __restrict__ x, unsigned short* __restrict__ xb) {
  size_t i = (size_t)(blockIdx.x * 256 + threadIdx.x) * 8;
  float4 a = *(const float4*)(x + i);
  float4 c = *(const float4*)(x + i + 4);
  ushort8 o;
  o[0] = f2bf(a.x); o[1] = f2bf(a.y); o[2] = f2bf(a.z); o[3] = f2bf(a.w);
  o[4] = f2bf(c.x); o[5] = f2bf(c.y); o[6] = f2bf(c.z); o[7] = f2bf(c.w);
  *(ushort8*)(xb + i) = o;
}

// dist_emb [2047][64] f32 -> [2048][64] bf16 * SC (row 2047 zero-padded)
__global__ void k0_cvt_pe(const float* __restrict__ de, unsigned short* __restrict__ peb) {
  size_t i = (size_t)(blockIdx.x * 256 + threadIdx.x) * 8;
  int row = (int)(i >> 6);
  ushort8 o;
  if (row < 2047) {
    float4 a = *(const float4*)(de + i);
    float4 c = *(const float4*)(de + i + 4);
    o[0] = f2bf(a.x * SC); o[1] = f2bf(a.y * SC); o[2] = f2bf(a.z * SC); o[3] = f2bf(a.w * SC);
    o[4] = f2bf(c.x * SC); o[5] = f2bf(c.y * SC); o[6] = f2bf(c.z * SC); o[7] = f2bf(c.w * SC);
  } else {
    o = ushort8{0, 0, 0, 0, 0, 0, 0, 0};
  }
  *(ushort8*)(peb + i) = o;
}

// W[k][n] f32 -> wt[sec*768+n][k] bf16  (64x64 LDS tile transpose)
__global__ __launch_bounds__(256) void k0_wt(const float* __restrict__ Wq,
                                             const float* __restrict__ Wk,
                                             const float* __restrict__ Wv,
                                             unsigned short* __restrict__ wt) {
  __shared__ float t[64][65];
  int bidx = blockIdx.x;                 // 3 * 12 * 12 = 432
  int sec = bidx / 144, rem = bidx % 144;
  int ktb = rem / 12, ntb = rem % 12;
  const float* W = (sec == 0) ? Wq : ((sec == 1) ? Wk : Wv);
  int k0 = ktb * 64, n0 = ntb * 64;
  int tid = threadIdx.x;
  #pragma unroll
  for (int p = 0; p < 4; ++p) {
    int id = p * 256 + tid;              // 0..1023
    int row = id >> 4, ch = id & 15;
    float4 v = *(const float4*)(W + (size_t)(k0 + row) * 768 + n0 + ch * 4);
    t[row][ch * 4 + 0] = v.x; t[row][ch * 4 + 1] = v.y;
    t[row][ch * 4 + 2] = v.z; t[row][ch * 4 + 3] = v.w;
  }
  __syncthreads();
  #pragma unroll
  for (int p = 0; p < 2; ++p) {
    int id = p * 256 + tid;              // 0..511
    int nrow = id >> 3, c8 = id & 7;
    ushort8 o;
    #pragma unroll
    for (int i = 0; i < 8; ++i) o[i] = f2bf(t[c8 * 8 + i][nrow]);
    *(ushort8*)(wt + (size_t)(sec * 768 + n0 + nrow) * 768 + k0 + c8 * 8) = o;
  }
}

// ------------------------------------------------- K1: fused QKV projection
// (proven 64x64-tile version; Q,K outputs scaled by SC)
__global__ __launch_bounds__(256) void k1_qkv(
    const unsigned short* __restrict__ xb, const unsigned short* __restrict__ wt,
    const float* __restrict__ bq, const float* __restrict__ bk, const float* __restrict__ bv,
    unsigned short* __restrict__ q_ws, unsigned short* __restrict__ k_ws,
    unsigned short* __restrict__ vt_ws) {
  __shared__ char ldsA[8192], ldsB[8192];
  const int tid = threadIdx.x, lane = tid & 63, wv = tid >> 6;
  const int row16 = lane & 15, cgrp = lane >> 4;
  const int ntb = blockIdx.x % 36, mtb = blockIdx.x / 36;
  const int sec = ntb / 12;
  const int n0 = ntb * 64;
  const int m0 = mtb * 64;

  f32x4 acc[4] = {zero4(), zero4(), zero4(), zero4()};

  for (int k0 = 0; k0 < 768; k0 += 64) {
    #pragma unroll
    for (int c = 0; c < 2; ++c) {
      int cc = (wv * 2 + c) * 64 + lane;
      int row = cc >> 3, ch = cc & 7, chs = ch ^ (row & 7);
      gload16(ldsA + (wv * 2 + c) * 1024, xb + (size_t)(m0 + row) * 768 + k0 + chs * 8);
      gload16(ldsB + (wv * 2 + c) * 1024, wt + (size_t)(n0 + row) * 768 + k0 + chs * 8);
    }
    __syncthreads();
    if (sec < 2) {
      bf16x8 af[2];
      #pragma unroll
      for (int k2 = 0; k2 < 2; ++k2) af[k2] = frag_ld(ldsA, wv * 16 + row16, k2 * 4 + cgrp);
      #pragma unroll
      for (int nt = 0; nt < 4; ++nt)
        #pragma unroll
        for (int k2 = 0; k2 < 2; ++k2) {
          bf16x8 bf = frag_ld(ldsB, nt * 16 + row16, k2 * 4 + cgrp);
          acc[nt] = mfma_bf16(af[k2], bf, acc[nt]);
        }
    } else {
      bf16x8 af[2];
      #pragma unroll
      for (int k2 = 0; k2 < 2; ++k2) af[k2] = frag_ld(ldsB, wv * 16 + row16, k2 * 4 + cgrp);
      #pragma unroll
      for (int mt = 0; mt < 4; ++mt)
        #pragma unroll
        for (int k2 = 0; k2 < 2; ++k2) {
          bf16x8 bx = frag_ld(ldsA, mt * 16 + row16, k2 * 4 + cgrp);
          acc[mt] = mfma_bf16(af[k2], bx, acc[mt]);
        }
    }
    __syncthreads();
  }

  if (sec < 2) {
    unsigned short* dst = (sec == 0) ? q_ws : k_ws;
    const float* bias = (sec == 0) ? bq : bk;
    int nl0 = (ntb % 12) * 64;
    #pragma unroll
    for (int nt = 0; nt < 4; ++nt) {
      int nn = nl0 + nt * 16 + row16;
      float bb = bias[nn];
      int hh = nn >> 6, dd = nn & 63;
      #pragma unroll
      for (int j = 0; j < 4; ++j) {
        int m = m0 + wv * 16 + cgrp * 4 + j;
        int b_ = m >> 10, s_ = m & 1023;
        dst[(size_t)((b_ * 12 + hh) * 1024 + s_) * 64 + dd] = f2bf((acc[nt][j] + bb) * SC);
      }
    }
  } else {
    int nl0 = (ntb % 12) * 64;
    #pragma unroll
    for (int j = 0; j < 4; ++j) {
      int nn = nl0 + wv * 16 + cgrp * 4 + j;
      float bb = bv[nn];
      int hh = nn >> 6, dd = nn & 63;
      #pragma unroll
      for (int mt = 0; mt < 4; ++mt) {
        int m = m0 + mt * 16 + row16;
        int b_ = m >> 10, s_ = m & 1023;
        vt_ws[(size_t)((b_ * 12 + hh) * 64 + dd) * 1024 + s_] = f2bf(acc[mt][j] + bb);
      }
    }
  }
}

// --------- K2: 2 score tiles per 512-thr block -> unnormalized p (bf16)
// grid 6144 = 48bh*16lt*8rq, XCD-chunked. Wave-quad `quad` handles tile
// rt = 2rq+quad (4 waves, 32x32 quadrants each). The 192-row PE window is
// staged ONCE for both tiles; s3 scratch aliases the dead 40KB K/PE staging
// region after b2 (kf/pef live in registers). LDS 57KB -> 2 blocks/CU
// (16 waves/CU, same as R12's 4x4 but 25% less PE staging, half the blocks).
__global__ __launch_bounds__(512) void k2_score(
    const unsigned short* __restrict__ q_ws, const unsigned short* __restrict__ k_ws,
    const unsigned short* __restrict__ peb, const float* __restrict__ mask,
    unsigned short* __restrict__ p_out, float* __restrict__ rsum_part) {
  __shared__ __align__(16) char stage_lds[40960];   // K0 8K | K1 8K | PE 24K
  __shared__ unsigned short p_sh[2][64 * 64];       // per-quad swizzled p tile
  __shared__ float rsum_sh[4][64];                  // [quad*2+wr][row]

  const int tid = threadIdx.x, lane = tid & 63;
  const int wv8 = tid >> 6;            // 0..7
  const int quad = wv8 >> 2;           // 0,1 -> tile
  const int wv = wv8 & 3;
  const int wl = wv >> 1, wr = wv & 1;
  const int row16 = lane & 15, cgrp = lane >> 4;

  const int bid = blockIdx.x;
  const int swz = (bid & 7) * 768 + (bid >> 3);   // 6144 = 8*768, bijective
  const int rq = swz & 7, lt = (swz >> 3) & 15, bh = swz >> 7;
  const int b = bh / NH;
  const int l0 = lt * 64;
  const int rt = rq * 2 + quad;
  const int r0 = rt * 64;

  const unsigned short* qh = q_ws + (size_t)bh * S * HD;
  const unsigned short* khp = k_ws + (size_t)bh * S * HD;
  const float* maskb = mask + b * S;

  char* k_lds = stage_lds + quad * 8192;
  char* pe_lds = stage_lds + 16384;
  const int peoff = 64 * (1 - quad);   // tile-local row -> union row

  // ---- stage own K tile [64][64] (per quad) ----
  #pragma unroll
  for (int c = 0; c < 2; ++c) {
    int cc = (wv * 2 + c) * 64 + lane;
    int row = cc >> 3, ch = cc & 7, chs = ch ^ (row & 7);
    gload16(k_lds + (wv * 2 + c) * 1024, khp + (size_t)(r0 + row) * HD + chs * 8);
  }
  // ---- stage shared PE union window [192][64] (all 8 waves) ----
  {
    int mU = l0 - rq * 128 - 64 + 960;   // in [0, 1856]; +191 <= 2047
    #pragma unroll
    for (int c = 0; c < 3; ++c) {
      int cc = (wv8 * 3 + c) * 64 + lane;
      int row = cc >> 3, ch = cc & 7, chs = ch ^ (row & 7);
      gload16(pe_lds + (wv8 * 3 + c) * 1024, peb + (size_t)(mU + row) * HD + chs * 8);
    }
  }

  // Q fragments straight from global (overlaps staging; same rows per quad)
  bf16x8 qf[2][2];
  #pragma unroll
  for (int ltl = 0; ltl < 2; ++ltl)
    #pragma unroll
    for (int k2 = 0; k2 < 2; ++k2)
      qf[ltl][k2] = *(const bf16x8*)(qh + (size_t)(l0 + wl * 32 + ltl * 16 + row16) * HD +
                                     k2 * 32 + cgrp * 8);
  __syncthreads();                                 // b1: staging visible

  // ---- fragment reads: K, PE -> registers ----
  bf16x8 kf[2][2], pef[4][2];
  #pragma unroll
  for (int rtl = 0; rtl < 2; ++rtl)
    #pragma unroll
    for (int k2 = 0; k2 < 2; ++k2)
      kf[rtl][k2] = frag_ld(k_lds, wr * 32 + rtl * 16 + row16, k2 * 4 + cgrp);
  const int qb = (wl - wr) * 32 + 32 + peoff;  // quadrant base within union
  #pragma unroll
  for (int jt = 0; jt < 4; ++jt)
    #pragma unroll
    for (int k2 = 0; k2 < 2; ++k2)
      pef[jt][k2] = frag_ld(pe_lds, qb + jt * 16 + row16, k2 * 4 + cgrp);
  __syncthreads();                                 // b2: staging LDS now dead

  // s3 scratch aliases the staging region: per-wave [64 jj][36 pad] bf16
  unsigned short* s3w = (unsigned short*)stage_lds + wv8 * (64 * 36);

  // ---- S3 = K @ PE^T -> per-wave LDS transposed [jj][r], bf16 ----
  #pragma unroll
  for (int rtl = 0; rtl < 2; ++rtl)
    #pragma unroll
    for (int jt = 0; jt < 4; ++jt) {
      f32x4 a3 = zero4();
      a3 = mfma_bf16(kf[rtl][0], pef[jt][0], a3);
      a3 = mfma_bf16(kf[rtl][1], pef[jt][1], a3);
      us4 o;
      o[0] = f2bf(a3[0]); o[1] = f2bf(a3[1]); o[2] = f2bf(a3[2]); o[3] = f2bf(a3[3]);
      *(us4*)(s3w + (jt * 16 + row16) * 36 + rtl * 16 + cgrp * 4) = o;
    }

  // ---- S1 = Q @ K^T ----
  f32x4 s1[2][2];
  #pragma unroll
  for (int ltl = 0; ltl < 2; ++ltl)
    #pragma unroll
    for (int rtl = 0; rtl < 2; ++rtl) {
      f32x4 a1 = zero4();
      a1 = mfma_bf16(qf[ltl][0], kf[rtl][0], a1);
      a1 = mfma_bf16(qf[ltl][1], kf[rtl][1], a1);
      s1[ltl][rtl] = a1;
    }
  // ---- S2 = Q @ PE^T (registers, gathered via shfl) ----
  f32x4 s2[2][4];
  #pragma unroll
  for (int ltl = 0; ltl < 2; ++ltl)
    #pragma unroll
    for (int jt = 0; jt < 4; ++jt) {
      f32x4 a2 = zero4();
      a2 = mfma_bf16(qf[ltl][0], pef[jt][0], a2);
      a2 = mfma_bf16(qf[ltl][1], pef[jt][1], a2);
      s2[ltl][jt] = a2;
    }

  // ---- combine: diag gathers + exp2 + p_sh + rowsum partials ----
  float rs[2][4] = {};
  #pragma unroll
  for (int rtl = 0; rtl < 2; ++rtl) {
    float mval = maskb[r0 + wr * 32 + rtl * 16 + row16] * LOG2E;
    #pragma unroll
    for (int ltl = 0; ltl < 2; ++ltl) {
      const int jtA = ltl - rtl + 1;
      #pragma unroll
      for (int j = 0; j < 4; ++j) {
        int dl = ltl * 16 + cgrp * 4 + j;
        int dr = rtl * 16 + row16;
        int jjq = dl - dr + 31;                       // [0,62]
        int src = (lane & 48) | (jjq & 15);
        float vA = __shfl(s2[ltl][jtA][j], src, 64);
        float vB = __shfl(s2[ltl][jtA + 1][j], src, 64);
        float b1 = ((jjq >> 4) == jtA) ? vA : vB;
        float b2 = bf2f(s3w[jjq * 36 + dr]);
        float p = exp2f(s1[ltl][rtl][j] + b1 + b2 + mval);
        rs[ltl][j] += p;
        int dlb = wl * 32 + dl, drb = wr * 32 + dr;
        p_sh[quad][dlb * 64 + (drb ^ ((dlb & 7) << 3))] = f2bf(p);
      }
    }
  }

  // ---- rowsum: reduce over the 16 dr lanes -> LDS partials ----
  #pragma unroll
  for (int ltl = 0; ltl < 2; ++ltl)
    #pragma unroll
    for (int j = 0; j < 4; ++j) {
      float v = rs[ltl][j];
      v += __shfl_xor(v, 1, 64);
      v += __shfl_xor(v, 2, 64);
      v += __shfl_xor(v, 4, 64);
      v += __shfl_xor(v, 8, 64);
      rs[ltl][j] = v;
    }
  if (row16 == 0) {
    #pragma unroll
    for (int ltl = 0; ltl < 2; ++ltl)
      #pragma unroll
      for (int j = 0; j < 4; ++j)
        rsum_sh[quad * 2 + wr][wl * 32 + ltl * 16 + cgrp * 4 + j] = rs[ltl][j];
  }
  __syncthreads();                                 // b3: p_sh + rsum_sh ready

  // one f32 per row per block (both tiles summed) -> [bh*16+lt][row][rq]
  if (tid < 64)
    rsum_part[((size_t)(bh * 16 + lt) * 64 + tid) * 8 + rq] =
        rsum_sh[0][tid] + rsum_sh[1][tid] + rsum_sh[2][tid] + rsum_sh[3][tid];

  // ---- coalesced p tile write-out (each quad writes its own tile) ----
  {
    const int t256 = tid & 255;
    #pragma unroll
    for (int p2 = 0; p2 < 2; ++p2) {
      int id = p2 * 256 + t256, dl = id >> 3, c = id & 7;
      uint4 w = *(const uint4*)((const char*)p_sh[quad] + dl * 128 + (c ^ (dl & 7)) * 16);
      *(uint4*)(p_out + ((size_t)bh * S + l0 + dl) * S + r0 + c * 8) = w;
    }
  }
}

// ---------------- K3: normalize probs (write f32) + PV GEMM + ctx epilogue
// grid: 768 blocks (8x96 XCD-chunked); double-buffered p tile in LDS.
__global__ __launch_bounds__(256) void k3_pv(
    const unsigned short* __restrict__ p_in, const unsigned short* __restrict__ vt_ws,
    const float* __restrict__ rsum_part, float* __restrict__ out_ctx,
    float* __restrict__ out_probs) {
  __shared__ char p_sh[2][8192];
  __shared__ float inv_sh[64];

  const int tid = threadIdx.x, lane = tid & 63, wv = tid >> 6;
  const int row16 = lane & 15, cgrp = lane >> 4;
  const int bid = blockIdx.x;
  const int swz = (bid & 7) * 96 + (bid >> 3);    // XCD-chunked (768 = 8*96)
  const int lt = swz & 15, bh = swz >> 4;
  const int b = bh / NH, h = bh % NH;
  const int l0 = lt * 64;

  const unsigned short* vth = vt_ws + (size_t)bh * HD * S;
  float* probs_bh = out_probs + (size_t)bh * S * S;

  if (tid < 64) {
    const float4* pp =
        (const float4*)(rsum_part + ((size_t)(bh * 16 + lt) * 64 + tid) * 8);
    float4 v0 = pp[0], v1 = pp[1];
    inv_sh[tid] = 1.0f / (v0.x + v0.y + v0.z + v0.w + v1.x + v1.y + v1.z + v1.w);
  }

  auto stage = [&](char* buf, int r0) {
    #pragma unroll
    for (int c = 0; c < 2; ++c) {
      int cc = (wv * 2 + c) * 64 + lane;
      int row = cc >> 3, ch = cc & 7, chs = ch ^ (row & 7);
      gload16(buf + (wv * 2 + c) * 1024,
              p_in + ((size_t)bh * S + l0 + row) * S + r0 + chs * 8);
    }
  };

  stage(p_sh[0], 0);
  __syncthreads();

  f32x4 ctxacc[4] = {zero4(), zero4(), zero4(), zero4()};

  for (int rt = 0; rt < 16; ++rt) {
    const int r0 = rt * 64, cur = rt & 1;
    if (rt < 15) stage(p_sh[cur ^ 1], r0 + 64);
    const char* cb = p_sh[cur];

    // normalized probs write (coalesced)
    #pragma unroll
    for (int p2 = 0; p2 < 2; ++p2) {
      int id = p2 * 256 + tid, dl = id >> 3, c = id & 7;
      uint4 w = *(const uint4*)(cb + dl * 128 + (c ^ (dl & 7)) * 16);
      const unsigned short* pu = (const unsigned short*)&w;
      float iv = inv_sh[dl];
      float* dst = probs_bh + (size_t)(l0 + dl) * S + r0 + c * 8;
      float4 lo{bf2f(pu[0]) * iv, bf2f(pu[1]) * iv, bf2f(pu[2]) * iv, bf2f(pu[3]) * iv};
      float4 hi{bf2f(pu[4]) * iv, bf2f(pu[5]) * iv, bf2f(pu[6]) * iv, bf2f(pu[7]) * iv};
      *(float4*)dst = lo; *(float4*)(dst + 4) = hi;
    }

    // PV accumulate (unnormalized p; ctx scaled at epilogue)
    {
      int lrow = wv * 16 + row16;
      bf16x8 pa[2];
      #pragma unroll
      for (int kc = 0; kc < 2; ++kc) {
        int ch = kc * 4 + cgrp, chs = ch ^ (lrow & 7);
        pa[kc] = *(const bf16x8*)(cb + lrow * 128 + chs * 16);
      }
      #pragma unroll
      for (int dt = 0; dt < 4; ++dt) {
        bf16x8 vb0 = *(const bf16x8*)(vth + (size_t)(dt * 16 + row16) * S + r0 + cgrp * 8);
        bf16x8 vb1 = *(const bf16x8*)(vth + (size_t)(dt * 16 + row16) * S + r0 + 32 + cgrp * 8);
        ctxacc[dt] = mfma_bf16(pa[0], vb0, ctxacc[dt]);
        ctxacc[dt] = mfma_bf16(pa[1], vb1, ctxacc[dt]);
      }
    }
    __syncthreads();
  }

  #pragma unroll
  for (int dt = 0; dt < 4; ++dt)
    #pragma unroll
    for (int j = 0; j < 4; ++j) {
      int lr = wv * 16 + cgrp * 4 + j;
      out_ctx[((size_t)(b * S + l0 + lr)) * HID + h * HD + dt * 16 + row16] =
          ctxacc[dt][j] * inv_sh[lr];
    }
}

}  // namespace

extern "C" void kernel_launch(void* const* d_in, const int* in_sizes, int n_in,
                              void* d_out, int out_size, void* d_ws, size_t ws_size,
                              hipStream_t stream) {
  const float* hidden = (const float*)d_in[0];
  const float* mask   = (const float*)d_in[1];
  const float* Wq = (const float*)d_in[2];
  const float* bq = (const float*)d_in[3];
  const float* Wk = (const float*)d_in[4];
  const float* bk = (const float*)d_in[5];
  const float* Wv = (const float*)d_in[6];
  const float* bv = (const float*)d_in[7];
  const float* de = (const float*)d_in[8];

  unsigned short* ws = (unsigned short*)d_ws;
  unsigned short* q_ws  = ws;                        // 48*1024*64
  unsigned short* k_ws  = ws + 3145728;
  unsigned short* vt_ws = ws + 6291456;              // [bh][d][s]
  unsigned short* xb    = ws + 9437184;              // [4096][768]
  unsigned short* wt    = ws + 12582912;             // [2304][768]
  unsigned short* peb   = ws + 14352384;             // [2048][64]
  float* rsum_part = (float*)(ws + 14483456);        // [768][64][8] f32
  unsigned short* p_ws  = ws + 16056320;             // [bh][l][r] bf16, 96MB
  // end = 66387968 shorts = 132.8 MB (ws ~816 MB per poison-fill size)

  float* outc = (float*)d_out;
  float* outp = outc + (size_t)4 * 1024 * 768;

  hipLaunchKernelGGL(k0_cvt_x, dim3(1536), dim3(256), 0, stream, hidden, xb);
  hipLaunchKernelGGL(k0_cvt_pe, dim3(64), dim3(256), 0, stream, de, peb);
  hipLaunchKernelGGL(k0_wt, dim3(432), dim3(256), 0, stream, Wq, Wk, Wv, wt);
  hipLaunchKernelGGL(k1_qkv, dim3(2304), dim3(256), 0, stream,
                     xb, wt, bq, bk, bv, q_ws, k_ws, vt_ws);
  hipLaunchKernelGGL(k2_score, dim3(6144), dim3(512), 0, stream,
                     q_ws, k_ws, peb, mask, p_ws, rsum_part);
  hipLaunchKernelGGL(k3_pv, dim3(768), dim3(256), 0, stream,
                     p_ws, vt_ws, rsum_part, outc, outp);
}